// Round 9
// baseline (318.528 us; speedup 1.0000x reference)
//
#include <hip/hip_runtime.h>
#include <hip/hip_bf16.h>
#include <math.h>

#define N_TOK 16384
#define BATCH 4
#define DIM   1024
#define HID   256
#define KEEP  11468            // int(16384 * 0.7)
#define MROWS 65536
#define NKT   32               // K-iters of 32
#define DELTA 6e-3f            // exact-recompute window around approx cut
#define WCAP  4096             // max window rows per batch

typedef __attribute__((ext_vector_type(8))) short bf16x8;
typedef __attribute__((ext_vector_type(4))) float f32x4;

__device__ inline unsigned bf16_rne(float f) {
    unsigned u = __float_as_uint(f);
    return (u + 0x7FFFu + ((u >> 16) & 1u)) >> 16;
}

__device__ inline unsigned cvt_pk_bf16(float lo, float hi) {
    unsigned r;
    asm("v_cvt_pk_bf16_f32 %0, %1, %2" : "=v"(r) : "v"(lo), "v"(hi));
    return r;
}

__device__ inline bf16x8 pack_bf16x8(float4 a, float4 b) {
    union { unsigned u[4]; bf16x8 v; } r;
    r.u[0] = cvt_pk_bf16(a.x, a.y);
    r.u[1] = cvt_pk_bf16(a.z, a.w);
    r.u[2] = cvt_pk_bf16(b.x, b.y);
    r.u[3] = cvt_pk_bf16(b.z, b.w);
    return r.v;
}

// ---------------------------------------------------------------------------
// prep: pack W1 (f32 [k][h]) into MFMA-B-fragment lines, bf16:
// line L = K32*16 + hg; within line: lane&15 = h offset, (lane>>4)*8+j = k.
// ---------------------------------------------------------------------------
__global__ __launch_bounds__(256) void prep_kernel(
    const float* __restrict__ W1, ushort* __restrict__ Wpk)
{
    const int kt = blockIdx.x;   // 0..15
    for (int idx = threadIdx.x; idx < 2048; idx += 256) {
        const int lane = idx & 63;
        const int g    = idx >> 6;        // 0..31
        const int h    = (g & 15) * 16 + (lane & 15);
        const int kb   = kt * 64 + (g >> 4) * 32 + (lane >> 4) * 8;
        ushort v[8];
#pragma unroll
        for (int j = 0; j < 8; ++j)
            v[j] = (ushort)bf16_rne(W1[(size_t)(kb + j) * HID + h]);
        *(uint4*)(Wpk + ((size_t)(kt * 32 + g) * 64 + lane) * 8) = *(uint4*)v;
    }
}

// ---------------------------------------------------------------------------
// score: scores = sigmoid(relu(x@W1+b1)@W2+b2), 1-pass bf16 MFMA.
// Barrier-free, LDS-free streaming loop, rotation pipeline:
//  - named registers cur/nxt/tmp rotated by copies (no modular indexing)
//  - B(kt) loads issued FIRST, then A(kt+2) prefetch: the MFMA's B-wait is
//    vmcnt(4), leaving the A loads in flight (2-iteration HBM slack)
//  - full unroll + sched_barrier(0) after load cluster = issue-early pinned
// 512 thr = 8 waves (2 wr x 4 wc), block 64 rows x 256 cols, wave 32x64.
// ---------------------------------------------------------------------------
__global__ __launch_bounds__(512, 4) void score_mfma(
    const float* __restrict__ x, const ushort* __restrict__ Wpk,
    const float* __restrict__ b1, const float* __restrict__ W2,
    const float* __restrict__ b2, float* __restrict__ scores,
    float* __restrict__ partials)
{
    __shared__ float zbuf[64][4];
    __shared__ float red[64];

    const int t    = threadIdx.x;
    const int lane = t & 63;
    const int w    = t >> 6;         // 0..7
    const int wr   = w >> 2;         // 0..1  (32 rows each)
    const int wc   = w & 3;          // 0..3  (64 cols each)
    const int l15  = lane & 15;
    const int lk   = lane >> 4;
    const size_t row0 = (size_t)blockIdx.x * 64;

    // A: lane reads x[row0 + wr*32 + {0,16} + l15][kt*32 + lk*8 .. +8]
    const float* a0 = x + (row0 + wr * 32 + l15) * DIM + lk * 8;
    const float* a1 = a0 + (size_t)16 * DIM;
    // B: fragment cf of K32=kt: Wpk + kt*8192 + ((wc*4+cf)*64 + lane)*8
    const ushort* bb = Wpk + ((size_t)(wc * 4) * 64 + lane) * 8;

    f32x4 acc[2][4];
#pragma unroll
    for (int rf = 0; rf < 2; ++rf)
#pragma unroll
        for (int cf = 0; cf < 4; ++cf) acc[rf][cf] = (f32x4){0.f, 0.f, 0.f, 0.f};

    // rotation registers: cur = A(kt), nxt = A(kt+1)
    float4 c0, c1, c2, c3, n0, n1, n2, n3;
    {
        const float4* q0 = (const float4*)a0;
        const float4* q1 = (const float4*)a1;
        c0 = q0[0]; c1 = q0[1]; c2 = q1[0]; c3 = q1[1];
    }
    {
        const float4* q0 = (const float4*)(a0 + 32);
        const float4* q1 = (const float4*)(a1 + 32);
        n0 = q0[0]; n1 = q0[1]; n2 = q1[0]; n3 = q1[1];
    }

#pragma unroll
    for (int kt = 0; kt < NKT; ++kt) {
        // ---- B(kt) loads FIRST (so the MFMA's wait leaves A in flight)
        const ushort* bp = bb + (size_t)kt * 8192;
        const bf16x8 B0 = *(const bf16x8*)(bp);
        const bf16x8 B1 = *(const bf16x8*)(bp + 512);
        const bf16x8 B2 = *(const bf16x8*)(bp + 1024);
        const bf16x8 B3 = *(const bf16x8*)(bp + 1536);
        // ---- A(kt+2) prefetch (clamped; redundant at the tail, harmless)
        const int ka = (kt + 2 < NKT) ? (kt + 2) : (NKT - 1);
        const float4* q0 = (const float4*)(a0 + (size_t)ka * 32);
        const float4* q1 = (const float4*)(a1 + (size_t)ka * 32);
        const float4 t0 = q0[0], t1 = q0[1], t2 = q1[0], t3 = q1[1];
        __builtin_amdgcn_sched_barrier(0);
        // ---- compute tile kt
        const bf16x8 af0 = pack_bf16x8(c0, c1);
        const bf16x8 af1 = pack_bf16x8(c2, c3);
        acc[0][0] = __builtin_amdgcn_mfma_f32_16x16x32_bf16(af0, B0, acc[0][0], 0, 0, 0);
        acc[1][0] = __builtin_amdgcn_mfma_f32_16x16x32_bf16(af1, B0, acc[1][0], 0, 0, 0);
        acc[0][1] = __builtin_amdgcn_mfma_f32_16x16x32_bf16(af0, B1, acc[0][1], 0, 0, 0);
        acc[1][1] = __builtin_amdgcn_mfma_f32_16x16x32_bf16(af1, B1, acc[1][1], 0, 0, 0);
        acc[0][2] = __builtin_amdgcn_mfma_f32_16x16x32_bf16(af0, B2, acc[0][2], 0, 0, 0);
        acc[1][2] = __builtin_amdgcn_mfma_f32_16x16x32_bf16(af1, B2, acc[1][2], 0, 0, 0);
        acc[0][3] = __builtin_amdgcn_mfma_f32_16x16x32_bf16(af0, B3, acc[0][3], 0, 0, 0);
        acc[1][3] = __builtin_amdgcn_mfma_f32_16x16x32_bf16(af1, B3, acc[1][3], 0, 0, 0);
        // ---- rotate
        c0 = n0; c1 = n1; c2 = n2; c3 = n3;
        n0 = t0; n1 = t1; n2 = t2; n3 = t3;
    }

    // epilogue: z = sum_h relu(C + b1) * W2; C row = lk*4+j, col = l15
    float b1r[4], w2r[4];
#pragma unroll
    for (int cf = 0; cf < 4; ++cf) {
        const int col = wc * 64 + cf * 16 + l15;
        b1r[cf] = b1[col];
        w2r[cf] = W2[col];
    }
#pragma unroll
    for (int rf = 0; rf < 2; ++rf) {
#pragma unroll
        for (int j = 0; j < 4; ++j) {
            float z = 0.f;
#pragma unroll
            for (int cf = 0; cf < 4; ++cf)
                z = fmaf(fmaxf(acc[rf][cf][j] + b1r[cf], 0.f), w2r[cf], z);
            z += __shfl_xor(z, 1);
            z += __shfl_xor(z, 2);
            z += __shfl_xor(z, 4);
            z += __shfl_xor(z, 8);
            if (l15 == 0) zbuf[wr * 32 + rf * 16 + lk * 4 + j][wc] = z;
        }
    }
    __syncthreads();
    if (t < 64) {
        const float z = (zbuf[t][0] + zbuf[t][1]) + (zbuf[t][2] + zbuf[t][3]) + b2[0];
        const float s = 1.f / (1.f + expf(-z));
        scores[row0 + t] = s;
        red[t] = fabsf(s - 0.5f);
    }
    __syncthreads();
    for (int off = 32; off > 0; off >>= 1) {
        if (t < off) red[t] += red[t + off];
        __syncthreads();
    }
    if (t == 0) partials[blockIdx.x] = red[0];
}

// ---------------------------------------------------------------------------
// fixfind: per batch, binary-search the approx k-th score, emit rows within
// +-DELTA (deterministic order by row index). Wave-parallel count reduce.
// ---------------------------------------------------------------------------
__global__ __launch_bounds__(1024) void fixfind_kernel(
    const float* __restrict__ scores, int* __restrict__ winList,
    int* __restrict__ winCnt)
{
    const int b    = blockIdx.x;
    const int t    = threadIdx.x;
    const int lane = t & 63;
    const int wid  = t >> 6;
    __shared__ unsigned red[17];
    __shared__ unsigned wsum[16];

    float sv[16];
    unsigned bits[16];
    const float4* sp = (const float4*)(scores + (size_t)b * N_TOK + t * 16);
#pragma unroll
    for (int j = 0; j < 4; ++j) {
        const float4 v = sp[j];
        sv[j * 4 + 0] = v.x; sv[j * 4 + 1] = v.y;
        sv[j * 4 + 2] = v.z; sv[j * 4 + 3] = v.w;
    }
#pragma unroll
    for (int j = 0; j < 16; ++j) bits[j] = __float_as_uint(sv[j]);

    auto countGE = [&](unsigned v) -> unsigned {
        unsigned c = 0;
#pragma unroll
        for (int j = 0; j < 16; ++j) c += (bits[j] >= v) ? 1u : 0u;
        c += __shfl_xor(c, 32); c += __shfl_xor(c, 16); c += __shfl_xor(c, 8);
        c += __shfl_xor(c, 4);  c += __shfl_xor(c, 2);  c += __shfl_xor(c, 1);
        if (lane == 0) red[wid] = c;
        __syncthreads();
        if (wid == 0) {
            unsigned s = (lane < 16) ? red[lane] : 0u;
            s += __shfl_xor(s, 8); s += __shfl_xor(s, 4);
            s += __shfl_xor(s, 2); s += __shfl_xor(s, 1);
            if (lane == 0) red[16] = s;
        }
        __syncthreads();
        return red[16];
    };

    unsigned lo = 0u, hi = 0x40000000u;
    while (hi - lo > 1u) {
        const unsigned mid = (lo + hi) >> 1;
        if (countGE(mid) >= KEEP) lo = mid; else hi = mid;
    }
    const float sT = __uint_as_float(lo);

    int cnt = 0;
    bool inw[16];
#pragma unroll
    for (int j = 0; j < 16; ++j) {
        inw[j] = fabsf(sv[j] - sT) <= DELTA;
        cnt += inw[j] ? 1 : 0;
    }
    unsigned inc = (unsigned)cnt;
#pragma unroll
    for (int off = 1; off < 64; off <<= 1) {
        const unsigned n = __shfl_up(inc, off);
        if (lane >= off) inc += n;
    }
    const unsigned excl = inc - (unsigned)cnt;
    if (lane == 63) wsum[wid] = inc;
    __syncthreads();
    if (t == 0) {
        unsigned s = 0;
        for (int w = 0; w < 16; ++w) { const unsigned tmp = wsum[w]; wsum[w] = s; s += tmp; }
        winCnt[b] = (int)(s > WCAP ? WCAP : s);
    }
    __syncthreads();
    unsigned pos = wsum[wid] + excl;
#pragma unroll
    for (int j = 0; j < 16; ++j) {
        if (inw[j]) {
            if (pos < WCAP) winList[b * WCAP + pos] = t * 16 + j;
            ++pos;
        }
    }
}

// ---------------------------------------------------------------------------
// fix2: exact f32 recompute of windowed rows, 8 rows/group, 1024 threads,
// k-dim split over 4 thread-quads. Grid-stride over groups.
// ---------------------------------------------------------------------------
__global__ __launch_bounds__(1024) void fix2_kernel(
    const float* __restrict__ x, const float* __restrict__ W1,
    const float* __restrict__ b1, const float* __restrict__ W2,
    const float* __restrict__ b2, float* __restrict__ scores,
    const int* __restrict__ winList, const int* __restrict__ winCnt)
{
    __shared__ float xrT[1024][8];
    __shared__ float part[4][8][256];
    __shared__ int rows[8];

    const int t = threadIdx.x;
    int c[4], cum[5];
    cum[0] = 0;
    for (int b = 0; b < 4; ++b) {
        int cc = winCnt[b];
        if (cc > WCAP) cc = WCAP;
        if (cc < 0) cc = 0;
        c[b] = cc;
        cum[b + 1] = cum[b] + ((cc + 7) >> 3);
    }
    for (int g = blockIdx.x; g < cum[4]; g += gridDim.x) {
        int b = 0;
        while (g >= cum[b + 1]) ++b;
        const int gi   = g - cum[b];
        const int nval = min(8, c[b] - gi * 8);
        if (t < 8)
            rows[t] = winList[b * WCAP + gi * 8 + (t < nval ? t : 0)];
        __syncthreads();
        {
            const int r = t >> 7, c0 = (t & 127) * 8;
            const float* xp = x + ((size_t)b * N_TOK + rows[r]) * DIM + c0;
            const float4 a = ((const float4*)xp)[0], bq = ((const float4*)xp)[1];
            xrT[c0 + 0][r] = a.x;  xrT[c0 + 1][r] = a.y;
            xrT[c0 + 2][r] = a.z;  xrT[c0 + 3][r] = a.w;
            xrT[c0 + 4][r] = bq.x; xrT[c0 + 5][r] = bq.y;
            xrT[c0 + 6][r] = bq.z; xrT[c0 + 7][r] = bq.w;
        }
        __syncthreads();
        const int h = t & 255, q = t >> 8;
        float a8[8];
#pragma unroll
        for (int r = 0; r < 8; ++r) a8[r] = 0.f;
        const int k0 = q * 256;
        for (int k = 0; k < 256; ++k) {
            const float wv = W1[(size_t)(k0 + k) * HID + h];
            const float4 xa = *(const float4*)&xrT[k0 + k][0];
            const float4 xb = *(const float4*)&xrT[k0 + k][4];
            a8[0] = fmaf(xa.x, wv, a8[0]); a8[1] = fmaf(xa.y, wv, a8[1]);
            a8[2] = fmaf(xa.z, wv, a8[2]); a8[3] = fmaf(xa.w, wv, a8[3]);
            a8[4] = fmaf(xb.x, wv, a8[4]); a8[5] = fmaf(xb.y, wv, a8[5]);
            a8[6] = fmaf(xb.z, wv, a8[6]); a8[7] = fmaf(xb.w, wv, a8[7]);
        }
#pragma unroll
        for (int r = 0; r < 8; ++r) part[q][r][h] = a8[r];
        __syncthreads();
        const int wid = t >> 6, lane = t & 63;
        if (wid < 8) {
            const int r = wid;
            float v = 0.f;
#pragma unroll
            for (int i = 0; i < 4; ++i) {
                const int hc = i * 64 + lane;
                float hv = (part[0][r][hc] + part[1][r][hc]) + (part[2][r][hc] + part[3][r][hc]);
                hv = fmaxf(hv + b1[hc], 0.f);
                v = fmaf(hv, W2[hc], v);
            }
            v += __shfl_xor(v, 32); v += __shfl_xor(v, 16); v += __shfl_xor(v, 8);
            v += __shfl_xor(v, 4);  v += __shfl_xor(v, 2);  v += __shfl_xor(v, 1);
            if (lane == 0 && r < nval)
                scores[(size_t)b * N_TOK + rows[r]] = 1.f / (1.f + expf(-(v + b2[0])));
        }
        __syncthreads();
    }
}

// ---------------------------------------------------------------------------
// select: exact top-k per batch on corrected scores; wave-parallel reduce.
// ---------------------------------------------------------------------------
__global__ __launch_bounds__(1024) void select_kernel(
    const float* __restrict__ scores, int* __restrict__ idxList)
{
    const int b    = blockIdx.x;
    const int t    = threadIdx.x;
    const int lane = t & 63;
    const int wid  = t >> 6;
    __shared__ unsigned red[17];

    unsigned bits[16];
    const float4* sp = (const float4*)(scores + (size_t)b * N_TOK + t * 16);
#pragma unroll
    for (int j = 0; j < 4; ++j) {
        const float4 v = sp[j];
        bits[j * 4 + 0] = __float_as_uint(v.x);
        bits[j * 4 + 1] = __float_as_uint(v.y);
        bits[j * 4 + 2] = __float_as_uint(v.z);
        bits[j * 4 + 3] = __float_as_uint(v.w);
    }

    auto countGE = [&](unsigned v) -> unsigned {
        unsigned c = 0;
#pragma unroll
        for (int j = 0; j < 16; ++j) c += (bits[j] >= v) ? 1u : 0u;
        c += __shfl_xor(c, 32); c += __shfl_xor(c, 16); c += __shfl_xor(c, 8);
        c += __shfl_xor(c, 4);  c += __shfl_xor(c, 2);  c += __shfl_xor(c, 1);
        if (lane == 0) red[wid] = c;
        __syncthreads();
        if (wid == 0) {
            unsigned s = (lane < 16) ? red[lane] : 0u;
            s += __shfl_xor(s, 8); s += __shfl_xor(s, 4);
            s += __shfl_xor(s, 2); s += __shfl_xor(s, 1);
            if (lane == 0) red[16] = s;
        }
        __syncthreads();
        return red[16];
    };

    unsigned lo = 0u, hi = 0x40000000u;
    while (hi - lo > 1u) {
        const unsigned mid = (lo + hi) >> 1;
        if (countGE(mid) >= KEEP) lo = mid; else hi = mid;
    }
    const unsigned T    = lo;
    const unsigned cGT  = countGE(T + 1u);
    const unsigned need = KEEP - cGT;

    unsigned pre[16];
    unsigned run = 0;
#pragma unroll
    for (int j = 0; j < 16; ++j) {
        pre[j] = run;
        const unsigned gt = (bits[j] > T) ? 1u : 0u;
        const unsigned eq = (bits[j] == T) ? 1u : 0u;
        run += gt | (eq << 16);
    }
    unsigned inc = run;
#pragma unroll
    for (int off = 1; off < 64; off <<= 1) {
        const unsigned n = __shfl_up(inc, off);
        if (lane >= off) inc += n;
    }
    const unsigned waveExcl = inc - run;
    if (lane == 63) red[wid] = inc;
    __syncthreads();
    if (t == 0) {
        unsigned s = 0;
        for (int w = 0; w < 16; ++w) { const unsigned tmp = red[w]; red[w] = s; s += tmp; }
    }
    __syncthreads();
    const unsigned base = red[wid] + waveExcl;

#pragma unroll
    for (int j = 0; j < 16; ++j) {
        const unsigned pe    = base + pre[j];
        const unsigned tieR  = pe >> 16;
        const unsigned posGT = pe & 0xFFFFu;
        const bool gt = bits[j] > T;
        const bool eq = bits[j] == T;
        if (gt || (eq && tieR < need)) {
            const unsigned pos = posGT + (tieR < need ? tieR : need);
            idxList[(size_t)b * KEEP + pos] = t * 16 + j;
        }
    }
}

// ---------------------------------------------------------------------------
// gather: weighted gather, float4 (HBM-bound, near roofline).
// ---------------------------------------------------------------------------
__global__ __launch_bounds__(256) void gather_kernel(
    const float* __restrict__ x, const float* __restrict__ scores,
    const int* __restrict__ idxList, float* __restrict__ out)
{
    const int t = threadIdx.x;
#pragma unroll
    for (int q = 0; q < 4; ++q) {
        const int orow = blockIdx.x * 4 + q;
        const int b    = orow / KEEP;
        const int idx  = idxList[orow];
        const float s  = scores[(size_t)b * N_TOK + idx];
        const float4 v = *(const float4*)(x + (((size_t)b * N_TOK + idx) << 10) + t * 4);
        float4 o;
        o.x = v.x * s; o.y = v.y * s; o.z = v.z * s; o.w = v.w * s;
        *(float4*)(out + ((size_t)orow << 10) + t * 4) = o;
    }
}

// ---------------------------------------------------------------------------
// loss: -mean(|s-0.5|) over 1024 block partials.
// ---------------------------------------------------------------------------
__global__ __launch_bounds__(256) void loss_kernel(
    const float* __restrict__ partials, float* __restrict__ outLoss)
{
    __shared__ float red[256];
    const int t = threadIdx.x;
    red[t] = (partials[t] + partials[t + 256]) + (partials[t + 512] + partials[t + 768]);
    __syncthreads();
    for (int off = 128; off > 0; off >>= 1) {
        if (t < off) red[t] += red[t + off];
        __syncthreads();
    }
    if (t == 0) outLoss[0] = -(red[0] / (float)MROWS);
}

extern "C" void kernel_launch(void* const* d_in, const int* in_sizes, int n_in,
                              void* d_out, int out_size, void* d_ws, size_t ws_size,
                              hipStream_t stream)
{
    const float* x  = (const float*)d_in[0];
    const float* W1 = (const float*)d_in[1];
    const float* b1 = (const float*)d_in[2];
    const float* W2 = (const float*)d_in[3];
    const float* b2 = (const float*)d_in[4];
    float* out = (float*)d_out;

    char* ws = (char*)d_ws;
    float* scores   = (float*)ws;                 // 262144 B
    float* partials = (float*)(ws + 262144);      // 4096 B (1024 used)
    int*   idxList  = (int*)(ws + 266240);        // 183488 B
    ushort* Wpk     = (ushort*)(ws + 458752);     // 524288 B
    int*   winList  = (int*)(ws + 983040);        // 65536 B
    int*   winCnt   = (int*)(ws + 1048576);       // 16 B

    prep_kernel<<<16, 256, 0, stream>>>(W1, Wpk);
    score_mfma<<<MROWS / 64, 512, 0, stream>>>(x, Wpk, b1, W2, b2, scores, partials);
    loss_kernel<<<1, 256, 0, stream>>>(partials, out + (size_t)BATCH * KEEP * DIM);
    fixfind_kernel<<<BATCH, 1024, 0, stream>>>(scores, winList, winCnt);
    fix2_kernel<<<256, 1024, 0, stream>>>(x, W1, b1, W2, b2, scores, winList, winCnt);
    select_kernel<<<BATCH, 1024, 0, stream>>>(scores, idxList);
    gather_kernel<<<KEEP, 256, 0, stream>>>(x, scores, idxList, out);
}

// Round 10
// 269.311 us; speedup vs baseline: 1.1828x; 1.1828x over previous
//
#include <hip/hip_runtime.h>
#include <hip/hip_bf16.h>
#include <math.h>

#define N_TOK 16384
#define BATCH 4
#define DIM   1024
#define HID   256
#define KEEP  11468            // int(16384 * 0.7)
#define MROWS 65536
#define RPB   32               // rows per score block
#define NKT   32               // K-iters of 32
#define DELTA 6e-3f            // exact-recompute window around approx cut
#define WCAP  4096             // max window rows per batch

typedef __attribute__((ext_vector_type(8))) short bf16x8;
typedef __attribute__((ext_vector_type(4))) float f32x4;

__device__ inline unsigned bf16_rne(float f) {
    unsigned u = __float_as_uint(f);
    return (u + 0x7FFFu + ((u >> 16) & 1u)) >> 16;
}

// ---------------------------------------------------------------------------
// prep: pack W1 (f32 [k][h]) into MFMA-B-fragment lines, bf16:
// line L = K32*16 + hg; within line: lane&15 = h offset, (lane>>4)*8+j = k.
// ---------------------------------------------------------------------------
__global__ __launch_bounds__(256) void prep_kernel(
    const float* __restrict__ W1, ushort* __restrict__ Wpk)
{
    const int kt = blockIdx.x;   // 0..15
    for (int idx = threadIdx.x; idx < 2048; idx += 256) {
        const int lane = idx & 63;
        const int g    = idx >> 6;        // 0..31
        const int h    = (g & 15) * 16 + (lane & 15);
        const int kb   = kt * 64 + (g >> 4) * 32 + (lane >> 4) * 8;
        ushort v[8];
#pragma unroll
        for (int j = 0; j < 8; ++j)
            v[j] = (ushort)bf16_rne(W1[(size_t)(kb + j) * HID + h]);
        *(uint4*)(Wpk + ((size_t)(kt * 32 + g) * 64 + lane) * 8) = *(uint4*)v;
    }
}

// ---------------------------------------------------------------------------
// score: scores = sigmoid(relu(x@W1+b1)@W2+b2), 1-pass bf16 MFMA.
// FULL-K-RESIDENT design:
//  Phase 1: stage 32 full x rows (128KB) with LINEAR COALESCED loads
//           (8KB contiguous per wave-step), f32->bf16, XOR-swizzled LDS.
//  Phase 2: barrier-free K-loop: A from LDS, B frags from L2-hot Wpk into
//           registers; plain unroll, no fences -> compiler pipelines.
// 512 thr = 8 waves (wr 0..1 x wc 0..3), wave tile 16 rows x 64 cols
// (acc[4] = 16 VGPR). LDS 65KB -> 2 blocks/CU: next block's staging
// overlaps this block's compute.
// ---------------------------------------------------------------------------
__global__ __launch_bounds__(512, 4) void score_mfma(
    const float* __restrict__ x, const ushort* __restrict__ Wpk,
    const float* __restrict__ b1, const float* __restrict__ W2,
    const float* __restrict__ b2, float* __restrict__ scores,
    float* __restrict__ partials)
{
    __shared__ ushort As[RPB * 1024];    // 64KB, swizzled row-major bf16
    __shared__ float zbuf[RPB][4];
    __shared__ float red[RPB];

    const int t    = threadIdx.x;
    const int lane = t & 63;
    const int w    = t >> 6;         // 0..7
    const int wr   = w >> 2;         // 0..1  (16 rows each)
    const int wc   = w & 3;          // 0..3  (64 cols each)
    const int l15  = lane & 15;
    const int lk   = lane >> 4;
    const size_t row0 = (size_t)blockIdx.x * RPB;

    // ---- Phase 1: linear coalesced staging of 32 rows ----
    {
        const float* xb = x + row0 * DIM;
#pragma unroll
        for (int i = 0; i < 16; ++i) {
            const int F   = i * 2048 + t * 4;       // flat float index
            const float4 v = *(const float4*)(xb + F);
            const int row = F >> 10;
            const int wb  = (F & 1023) * 2;         // byte offset in row (mult of 8)
            const int sw  = (row & 7) << 4;
            const int wbs = (((wb & ~15) ^ sw) | (wb & 15));
            uint2 hb;
            hb.x = bf16_rne(v.x) | (bf16_rne(v.y) << 16);
            hb.y = bf16_rne(v.z) | (bf16_rne(v.w) << 16);
            *(uint2*)((char*)As + row * 2048 + wbs) = hb;
        }
    }
    __syncthreads();

    // ---- Phase 2: barrier-free K-loop ----
    f32x4 acc[4];
#pragma unroll
    for (int cf = 0; cf < 4; ++cf) acc[cf] = (f32x4){0.f, 0.f, 0.f, 0.f};

    const int r = wr * 16 + l15;                  // A row for this lane
    const char* arow = (const char*)As + r * 2048;
    const int sw = (r & 7) << 4;
    const ushort* bb = Wpk + ((size_t)(wc * 4) * 64 + lane) * 8;

#pragma unroll
    for (int kt = 0; kt < NKT; ++kt) {
        const ushort* bp = bb + (size_t)kt * 8192;
        const bf16x8 B0 = *(const bf16x8*)(bp);
        const bf16x8 B1 = *(const bf16x8*)(bp + 512);
        const bf16x8 B2 = *(const bf16x8*)(bp + 1024);
        const bf16x8 B3 = *(const bf16x8*)(bp + 1536);
        const bf16x8 af = *(const bf16x8*)(arow + ((kt * 64 + lk * 16) ^ sw));
        acc[0] = __builtin_amdgcn_mfma_f32_16x16x32_bf16(af, B0, acc[0], 0, 0, 0);
        acc[1] = __builtin_amdgcn_mfma_f32_16x16x32_bf16(af, B1, acc[1], 0, 0, 0);
        acc[2] = __builtin_amdgcn_mfma_f32_16x16x32_bf16(af, B2, acc[2], 0, 0, 0);
        acc[3] = __builtin_amdgcn_mfma_f32_16x16x32_bf16(af, B3, acc[3], 0, 0, 0);
    }

    // ---- epilogue: z = sum_h relu(C + b1) * W2; C row = lk*4+j, col = l15
    float b1r[4], w2r[4];
#pragma unroll
    for (int cf = 0; cf < 4; ++cf) {
        const int col = wc * 64 + cf * 16 + l15;
        b1r[cf] = b1[col];
        w2r[cf] = W2[col];
    }
#pragma unroll
    for (int j = 0; j < 4; ++j) {
        float z = 0.f;
#pragma unroll
        for (int cf = 0; cf < 4; ++cf)
            z = fmaf(fmaxf(acc[cf][j] + b1r[cf], 0.f), w2r[cf], z);
        z += __shfl_xor(z, 1);
        z += __shfl_xor(z, 2);
        z += __shfl_xor(z, 4);
        z += __shfl_xor(z, 8);
        if (l15 == 0) zbuf[wr * 16 + lk * 4 + j][wc] = z;
    }
    __syncthreads();
    if (t < RPB) {
        const float z = (zbuf[t][0] + zbuf[t][1]) + (zbuf[t][2] + zbuf[t][3]) + b2[0];
        const float s = 1.f / (1.f + expf(-z));
        scores[row0 + t] = s;
        red[t] = fabsf(s - 0.5f);
    }
    __syncthreads();
    for (int off = 16; off > 0; off >>= 1) {
        if (t < off) red[t] += red[t + off];
        __syncthreads();
    }
    if (t == 0) partials[blockIdx.x] = red[0];
}

// ---------------------------------------------------------------------------
// fixfind: per batch, binary-search the approx k-th score, emit rows within
// +-DELTA (deterministic order by row index). Wave-parallel count reduce.
// ---------------------------------------------------------------------------
__global__ __launch_bounds__(1024) void fixfind_kernel(
    const float* __restrict__ scores, int* __restrict__ winList,
    int* __restrict__ winCnt)
{
    const int b    = blockIdx.x;
    const int t    = threadIdx.x;
    const int lane = t & 63;
    const int wid  = t >> 6;
    __shared__ unsigned red[17];
    __shared__ unsigned wsum[16];

    float sv[16];
    unsigned bits[16];
    const float4* sp = (const float4*)(scores + (size_t)b * N_TOK + t * 16);
#pragma unroll
    for (int j = 0; j < 4; ++j) {
        const float4 v = sp[j];
        sv[j * 4 + 0] = v.x; sv[j * 4 + 1] = v.y;
        sv[j * 4 + 2] = v.z; sv[j * 4 + 3] = v.w;
    }
#pragma unroll
    for (int j = 0; j < 16; ++j) bits[j] = __float_as_uint(sv[j]);

    auto countGE = [&](unsigned v) -> unsigned {
        unsigned c = 0;
#pragma unroll
        for (int j = 0; j < 16; ++j) c += (bits[j] >= v) ? 1u : 0u;
        c += __shfl_xor(c, 32); c += __shfl_xor(c, 16); c += __shfl_xor(c, 8);
        c += __shfl_xor(c, 4);  c += __shfl_xor(c, 2);  c += __shfl_xor(c, 1);
        if (lane == 0) red[wid] = c;
        __syncthreads();
        if (wid == 0) {
            unsigned s = (lane < 16) ? red[lane] : 0u;
            s += __shfl_xor(s, 8); s += __shfl_xor(s, 4);
            s += __shfl_xor(s, 2); s += __shfl_xor(s, 1);
            if (lane == 0) red[16] = s;
        }
        __syncthreads();
        return red[16];
    };

    unsigned lo = 0u, hi = 0x40000000u;
    while (hi - lo > 1u) {
        const unsigned mid = (lo + hi) >> 1;
        if (countGE(mid) >= KEEP) lo = mid; else hi = mid;
    }
    const float sT = __uint_as_float(lo);

    int cnt = 0;
    bool inw[16];
#pragma unroll
    for (int j = 0; j < 16; ++j) {
        inw[j] = fabsf(sv[j] - sT) <= DELTA;
        cnt += inw[j] ? 1 : 0;
    }
    unsigned inc = (unsigned)cnt;
#pragma unroll
    for (int off = 1; off < 64; off <<= 1) {
        const unsigned n = __shfl_up(inc, off);
        if (lane >= off) inc += n;
    }
    const unsigned excl = inc - (unsigned)cnt;
    if (lane == 63) wsum[wid] = inc;
    __syncthreads();
    if (t == 0) {
        unsigned s = 0;
        for (int w = 0; w < 16; ++w) { const unsigned tmp = wsum[w]; wsum[w] = s; s += tmp; }
        winCnt[b] = (int)(s > WCAP ? WCAP : s);
    }
    __syncthreads();
    unsigned pos = wsum[wid] + excl;
#pragma unroll
    for (int j = 0; j < 16; ++j) {
        if (inw[j]) {
            if (pos < WCAP) winList[b * WCAP + pos] = t * 16 + j;
            ++pos;
        }
    }
}

// ---------------------------------------------------------------------------
// fix2: exact f32 recompute of windowed rows, 8 rows/group, 1024 threads,
// k-dim split over 4 thread-quads. Grid-stride over groups.
// ---------------------------------------------------------------------------
__global__ __launch_bounds__(1024) void fix2_kernel(
    const float* __restrict__ x, const float* __restrict__ W1,
    const float* __restrict__ b1, const float* __restrict__ W2,
    const float* __restrict__ b2, float* __restrict__ scores,
    const int* __restrict__ winList, const int* __restrict__ winCnt)
{
    __shared__ float xrT[1024][8];
    __shared__ float part[4][8][256];
    __shared__ int rows[8];

    const int t = threadIdx.x;
    int c[4], cum[5];
    cum[0] = 0;
    for (int b = 0; b < 4; ++b) {
        int cc = winCnt[b];
        if (cc > WCAP) cc = WCAP;
        if (cc < 0) cc = 0;
        c[b] = cc;
        cum[b + 1] = cum[b] + ((cc + 7) >> 3);
    }
    for (int g = blockIdx.x; g < cum[4]; g += gridDim.x) {
        int b = 0;
        while (g >= cum[b + 1]) ++b;
        const int gi   = g - cum[b];
        const int nval = min(8, c[b] - gi * 8);
        if (t < 8)
            rows[t] = winList[b * WCAP + gi * 8 + (t < nval ? t : 0)];
        __syncthreads();
        {
            const int r = t >> 7, c0 = (t & 127) * 8;
            const float* xp = x + ((size_t)b * N_TOK + rows[r]) * DIM + c0;
            const float4 a = ((const float4*)xp)[0], bq = ((const float4*)xp)[1];
            xrT[c0 + 0][r] = a.x;  xrT[c0 + 1][r] = a.y;
            xrT[c0 + 2][r] = a.z;  xrT[c0 + 3][r] = a.w;
            xrT[c0 + 4][r] = bq.x; xrT[c0 + 5][r] = bq.y;
            xrT[c0 + 6][r] = bq.z; xrT[c0 + 7][r] = bq.w;
        }
        __syncthreads();
        const int h = t & 255, q = t >> 8;
        float a8[8];
#pragma unroll
        for (int r = 0; r < 8; ++r) a8[r] = 0.f;
        const int k0 = q * 256;
        for (int k = 0; k < 256; ++k) {
            const float wv = W1[(size_t)(k0 + k) * HID + h];
            const float4 xa = *(const float4*)&xrT[k0 + k][0];
            const float4 xb = *(const float4*)&xrT[k0 + k][4];
            a8[0] = fmaf(xa.x, wv, a8[0]); a8[1] = fmaf(xa.y, wv, a8[1]);
            a8[2] = fmaf(xa.z, wv, a8[2]); a8[3] = fmaf(xa.w, wv, a8[3]);
            a8[4] = fmaf(xb.x, wv, a8[4]); a8[5] = fmaf(xb.y, wv, a8[5]);
            a8[6] = fmaf(xb.z, wv, a8[6]); a8[7] = fmaf(xb.w, wv, a8[7]);
        }
#pragma unroll
        for (int r = 0; r < 8; ++r) part[q][r][h] = a8[r];
        __syncthreads();
        const int wid = t >> 6, lane = t & 63;
        if (wid < 8) {
            const int r = wid;
            float v = 0.f;
#pragma unroll
            for (int i = 0; i < 4; ++i) {
                const int hc = i * 64 + lane;
                float hv = (part[0][r][hc] + part[1][r][hc]) + (part[2][r][hc] + part[3][r][hc]);
                hv = fmaxf(hv + b1[hc], 0.f);
                v = fmaf(hv, W2[hc], v);
            }
            v += __shfl_xor(v, 32); v += __shfl_xor(v, 16); v += __shfl_xor(v, 8);
            v += __shfl_xor(v, 4);  v += __shfl_xor(v, 2);  v += __shfl_xor(v, 1);
            if (lane == 0 && r < nval)
                scores[(size_t)b * N_TOK + rows[r]] = 1.f / (1.f + expf(-(v + b2[0])));
        }
        __syncthreads();
    }
}

// ---------------------------------------------------------------------------
// select: exact top-k per batch on corrected scores; wave-parallel reduce.
// ---------------------------------------------------------------------------
__global__ __launch_bounds__(1024) void select_kernel(
    const float* __restrict__ scores, int* __restrict__ idxList)
{
    const int b    = blockIdx.x;
    const int t    = threadIdx.x;
    const int lane = t & 63;
    const int wid  = t >> 6;
    __shared__ unsigned red[17];

    unsigned bits[16];
    const float4* sp = (const float4*)(scores + (size_t)b * N_TOK + t * 16);
#pragma unroll
    for (int j = 0; j < 4; ++j) {
        const float4 v = sp[j];
        bits[j * 4 + 0] = __float_as_uint(v.x);
        bits[j * 4 + 1] = __float_as_uint(v.y);
        bits[j * 4 + 2] = __float_as_uint(v.z);
        bits[j * 4 + 3] = __float_as_uint(v.w);
    }

    auto countGE = [&](unsigned v) -> unsigned {
        unsigned c = 0;
#pragma unroll
        for (int j = 0; j < 16; ++j) c += (bits[j] >= v) ? 1u : 0u;
        c += __shfl_xor(c, 32); c += __shfl_xor(c, 16); c += __shfl_xor(c, 8);
        c += __shfl_xor(c, 4);  c += __shfl_xor(c, 2);  c += __shfl_xor(c, 1);
        if (lane == 0) red[wid] = c;
        __syncthreads();
        if (wid == 0) {
            unsigned s = (lane < 16) ? red[lane] : 0u;
            s += __shfl_xor(s, 8); s += __shfl_xor(s, 4);
            s += __shfl_xor(s, 2); s += __shfl_xor(s, 1);
            if (lane == 0) red[16] = s;
        }
        __syncthreads();
        return red[16];
    };

    unsigned lo = 0u, hi = 0x40000000u;
    while (hi - lo > 1u) {
        const unsigned mid = (lo + hi) >> 1;
        if (countGE(mid) >= KEEP) lo = mid; else hi = mid;
    }
    const unsigned T    = lo;
    const unsigned cGT  = countGE(T + 1u);
    const unsigned need = KEEP - cGT;

    unsigned pre[16];
    unsigned run = 0;
#pragma unroll
    for (int j = 0; j < 16; ++j) {
        pre[j] = run;
        const unsigned gt = (bits[j] > T) ? 1u : 0u;
        const unsigned eq = (bits[j] == T) ? 1u : 0u;
        run += gt | (eq << 16);
    }
    unsigned inc = run;
#pragma unroll
    for (int off = 1; off < 64; off <<= 1) {
        const unsigned n = __shfl_up(inc, off);
        if (lane >= off) inc += n;
    }
    const unsigned waveExcl = inc - run;
    if (lane == 63) red[wid] = inc;
    __syncthreads();
    if (t == 0) {
        unsigned s = 0;
        for (int w = 0; w < 16; ++w) { const unsigned tmp = red[w]; red[w] = s; s += tmp; }
    }
    __syncthreads();
    const unsigned base = red[wid] + waveExcl;

#pragma unroll
    for (int j = 0; j < 16; ++j) {
        const unsigned pe    = base + pre[j];
        const unsigned tieR  = pe >> 16;
        const unsigned posGT = pe & 0xFFFFu;
        const bool gt = bits[j] > T;
        const bool eq = bits[j] == T;
        if (gt || (eq && tieR < need)) {
            const unsigned pos = posGT + (tieR < need ? tieR : need);
            idxList[(size_t)b * KEEP + pos] = t * 16 + j;
        }
    }
}

// ---------------------------------------------------------------------------
// gather: weighted gather, float4 (HBM-bound, near roofline).
// ---------------------------------------------------------------------------
__global__ __launch_bounds__(256) void gather_kernel(
    const float* __restrict__ x, const float* __restrict__ scores,
    const int* __restrict__ idxList, float* __restrict__ out)
{
    const int t = threadIdx.x;
#pragma unroll
    for (int q = 0; q < 4; ++q) {
        const int orow = blockIdx.x * 4 + q;
        const int b    = orow / KEEP;
        const int idx  = idxList[orow];
        const float s  = scores[(size_t)b * N_TOK + idx];
        const float4 v = *(const float4*)(x + (((size_t)b * N_TOK + idx) << 10) + t * 4);
        float4 o;
        o.x = v.x * s; o.y = v.y * s; o.z = v.z * s; o.w = v.w * s;
        *(float4*)(out + ((size_t)orow << 10) + t * 4) = o;
    }
}

// ---------------------------------------------------------------------------
// loss: -mean(|s-0.5|) over 2048 block partials.
// ---------------------------------------------------------------------------
__global__ __launch_bounds__(256) void loss_kernel(
    const float* __restrict__ partials, float* __restrict__ outLoss)
{
    __shared__ float red[256];
    const int t = threadIdx.x;
    float s = 0.f;
#pragma unroll
    for (int i = 0; i < 8; ++i) s += partials[t + 256 * i];
    red[t] = s;
    __syncthreads();
    for (int off = 128; off > 0; off >>= 1) {
        if (t < off) red[t] += red[t + off];
        __syncthreads();
    }
    if (t == 0) outLoss[0] = -(red[0] / (float)MROWS);
}

extern "C" void kernel_launch(void* const* d_in, const int* in_sizes, int n_in,
                              void* d_out, int out_size, void* d_ws, size_t ws_size,
                              hipStream_t stream)
{
    const float* x  = (const float*)d_in[0];
    const float* W1 = (const float*)d_in[1];
    const float* b1 = (const float*)d_in[2];
    const float* W2 = (const float*)d_in[3];
    const float* b2 = (const float*)d_in[4];
    float* out = (float*)d_out;

    char* ws = (char*)d_ws;
    float* scores   = (float*)ws;                 // 262144 B
    float* partials = (float*)(ws + 262144);      // 8192 B (2048 used)
    int*   idxList  = (int*)(ws + 270336);        // 183488 B
    ushort* Wpk     = (ushort*)(ws + 458752);     // 524288 B
    int*   winList  = (int*)(ws + 983040);        // 65536 B
    int*   winCnt   = (int*)(ws + 1048576);       // 16 B

    prep_kernel<<<16, 256, 0, stream>>>(W1, Wpk);
    score_mfma<<<MROWS / RPB, 512, 0, stream>>>(x, Wpk, b1, W2, b2, scores, partials);
    loss_kernel<<<1, 256, 0, stream>>>(partials, out + (size_t)BATCH * KEEP * DIM);
    fixfind_kernel<<<BATCH, 1024, 0, stream>>>(scores, winList, winCnt);
    fix2_kernel<<<256, 1024, 0, stream>>>(x, W1, b1, W2, b2, scores, winList, winCnt);
    select_kernel<<<BATCH, 1024, 0, stream>>>(scores, idxList);
    gather_kernel<<<KEEP, 256, 0, stream>>>(x, scores, idxList, out);
}

// Round 11
// 239.346 us; speedup vs baseline: 1.3308x; 1.1252x over previous
//
#include <hip/hip_runtime.h>
#include <hip/hip_bf16.h>
#include <math.h>

#define N_TOK 16384
#define BATCH 4
#define DIM   1024
#define HID   256
#define KEEP  11468            // int(16384 * 0.7)
#define MROWS 65536
#define BM    256              // rows per block
#define NK2   16               // K-steps of 64
#define DELTA 6e-3f            // exact-recompute window around approx cut
#define WCAP  4096             // max window rows per batch

typedef __attribute__((ext_vector_type(8))) short bf16x8;
typedef __attribute__((ext_vector_type(4))) float f32x4;

__device__ inline unsigned bf16_rne(float f) {
    unsigned u = __float_as_uint(f);
    return (u + 0x7FFFu + ((u >> 16) & 1u)) >> 16;
}

#define GLDS16(gp, lp) __builtin_amdgcn_global_load_lds( \
    (const __attribute__((address_space(1))) void*)(gp), \
    (__attribute__((address_space(3))) void*)(lp), 16, 0, 0)

// ---------------------------------------------------------------------------
// prep: pack W1 (f32 [k][h]) into MFMA-B-fragment lines, bf16 (verified r2+):
// line L (global) = kt*32 + ks*16 + hg; within line: lane&15 = h offset,
// (lane>>4)*8+j = k offset; 16B per lane.
// ---------------------------------------------------------------------------
__global__ __launch_bounds__(256) void prep_kernel(
    const float* __restrict__ W1, ushort* __restrict__ Wpk)
{
    const int kt = blockIdx.x;   // 0..15
    for (int idx = threadIdx.x; idx < 2048; idx += 256) {
        const int lane = idx & 63;
        const int g    = idx >> 6;        // 0..31
        const int h    = (g & 15) * 16 + (lane & 15);
        const int kb   = kt * 64 + (g >> 4) * 32 + (lane >> 4) * 8;
        ushort v[8];
#pragma unroll
        for (int j = 0; j < 8; ++j)
            v[j] = (ushort)bf16_rne(W1[(size_t)(kb + j) * HID + h]);
        *(uint4*)(Wpk + ((size_t)(kt * 32 + g) * 64 + lane) * 8) = *(uint4*)v;
    }
}

// ---------------------------------------------------------------------------
// score: scores = sigmoid(relu(x@W1+b1)@W2+b2), 1-pass bf16 MFMA.
// 2-phase 256x256 template (BK=64): grid=256 (1 block/CU), 512 thr = 8 waves
// (wr 0..1 x wc 0..3), per-wave output 128x64 (acc[8][4]).
// A: dbuf XOR-swizzled LDS [2][256][64]bf16, reg-staged f32->bf16.
// B: dbuf linear LDS [2][32 x 1KB lines] via global_load_lds from Wpk.
// Per K-step: issue loads(t+1) -> sched_barrier -> ds_read+64 MFMA/wave ->
// convert+ds_write A(t+1) -> one barrier. 64 MFMA per barrier-pair.
// ---------------------------------------------------------------------------
__global__ __launch_bounds__(512, 2) void score_mfma(
    const float* __restrict__ x, const ushort* __restrict__ Wpk,
    const float* __restrict__ b1, const float* __restrict__ W2,
    const float* __restrict__ b2, float* __restrict__ scores,
    float* __restrict__ partials)
{
    __shared__ ushort As[2][BM * 64];     // 2 x 32KB, swizzled
    __shared__ ushort Bs[2][32 * 512];    // 2 x 32KB, fragment lines
    __shared__ float zbuf[BM][4];
    __shared__ float red[BM];

    const int t    = threadIdx.x;
    const int lane = t & 63;
    const int w    = t >> 6;          // 0..7
    const int wr   = w >> 2;          // 0..1  (128 rows each)
    const int wc   = w & 3;           // 0..3  (64 cols each)
    const int l15  = lane & 15;
    const int lk   = lane >> 4;
    const size_t row0 = (size_t)blockIdx.x * BM;

    // A staging role: thread -> (row, 32-float half of the 64-k slice)
    const int arow  = t >> 1;         // 0..255
    const int ahalf = t & 1;          // 0..1
    const float* xbase = x + (row0 + arow) * DIM + ahalf * 32;
    const int aswz = (arow & 7) << 4;
    // B staging: wave w stages lines w*4 .. w*4+3
    // B compute base for this wave's columns:
    const ushort* bb = Wpk;           // indexed per step

    f32x4 acc[8][4];
#pragma unroll
    for (int rf = 0; rf < 8; ++rf)
#pragma unroll
        for (int cf = 0; cf < 4; ++cf) acc[rf][cf] = (f32x4){0.f, 0.f, 0.f, 0.f};

    float pf[32];

#define LOADA(KT) { const float4* xp = (const float4*)(xbase + (size_t)(KT) * 64); \
        _Pragma("unroll") \
        for (int j = 0; j < 8; ++j) *(float4*)&pf[j * 4] = xp[j]; }
#define STOREA(BUF) { \
        unsigned hb[16]; \
        _Pragma("unroll") \
        for (int j = 0; j < 16; ++j) \
            hb[j] = bf16_rne(pf[2 * j]) | (bf16_rne(pf[2 * j + 1]) << 16); \
        char* base_ = (char*)&As[BUF][0] + arow * 128; \
        _Pragma("unroll") \
        for (int j = 0; j < 4; ++j) \
            *(uint4*)(base_ + ((ahalf * 64 + j * 16) ^ aswz)) = *(uint4*)&hb[j * 4]; }
#define LOADB(KT, BUF) { \
        _Pragma("unroll") \
        for (int i = 0; i < 4; ++i) { \
            const int line_ = w * 4 + i; \
            GLDS16(Wpk + (((size_t)(KT) * 32 + line_) * 64 + lane) * 8, \
                   &Bs[BUF][line_ * 512 + lane * 8]); \
        } }

    // ---- prologue: stage step 0
    LOADB(0, 0);
    LOADA(0);
    STOREA(0);
    __syncthreads();

    for (int kt = 0; kt < NK2; ++kt) {
        const int cur = kt & 1;
        const int nxt = cur ^ 1;
        if (kt < NK2 - 1) {
            LOADA(kt + 1);
            LOADB(kt + 1, nxt);
        }
        __builtin_amdgcn_sched_barrier(0);
#pragma unroll
        for (int ks = 0; ks < 2; ++ks) {
            bf16x8 Af[8];
#pragma unroll
            for (int rf = 0; rf < 8; ++rf) {
                const int r = wr * 128 + rf * 16 + l15;
                const int kb = (ks * 64 + lk * 16) ^ ((r & 7) << 4);
                Af[rf] = *(const bf16x8*)((const char*)&As[cur][0] + r * 128 + kb);
            }
            bf16x8 Bf[4];
#pragma unroll
            for (int cf = 0; cf < 4; ++cf)
                Bf[cf] = *(const bf16x8*)&Bs[cur][(ks * 16 + wc * 4 + cf) * 512 + lane * 8];
#pragma unroll
            for (int cf = 0; cf < 4; ++cf)
#pragma unroll
                for (int rf = 0; rf < 8; ++rf)
                    acc[rf][cf] = __builtin_amdgcn_mfma_f32_16x16x32_bf16(
                        Af[rf], Bf[cf], acc[rf][cf], 0, 0, 0);
        }
        if (kt < NK2 - 1) STOREA(nxt);
        __syncthreads();
    }

    // ---- epilogue: z = sum_h relu(C + b1) * W2; C row = lk*4+j, col = l15
    float b1r[4], w2r[4];
#pragma unroll
    for (int cf = 0; cf < 4; ++cf) {
        const int col = wc * 64 + cf * 16 + l15;
        b1r[cf] = b1[col];
        w2r[cf] = W2[col];
    }
#pragma unroll
    for (int rf = 0; rf < 8; ++rf) {
#pragma unroll
        for (int j = 0; j < 4; ++j) {
            float z = 0.f;
#pragma unroll
            for (int cf = 0; cf < 4; ++cf)
                z = fmaf(fmaxf(acc[rf][cf][j] + b1r[cf], 0.f), w2r[cf], z);
            z += __shfl_xor(z, 1);
            z += __shfl_xor(z, 2);
            z += __shfl_xor(z, 4);
            z += __shfl_xor(z, 8);
            if (l15 == 0) zbuf[wr * 128 + rf * 16 + lk * 4 + j][wc] = z;
        }
    }
    __syncthreads();
    if (t < BM) {
        const float z = (zbuf[t][0] + zbuf[t][1]) + (zbuf[t][2] + zbuf[t][3]) + b2[0];
        const float s = 1.f / (1.f + expf(-z));
        scores[row0 + t] = s;
        red[t] = fabsf(s - 0.5f);
    }
    __syncthreads();
    for (int off = 128; off > 0; off >>= 1) {
        if (t < off && t + off < BM) red[t] += red[t + off];
        __syncthreads();
    }
    if (t == 0) partials[blockIdx.x] = red[0];
}

// ---------------------------------------------------------------------------
// fixfind: per batch, binary-search the approx k-th score, emit rows within
// +-DELTA (deterministic order by row index). Wave-parallel count reduce.
// ---------------------------------------------------------------------------
__global__ __launch_bounds__(1024) void fixfind_kernel(
    const float* __restrict__ scores, int* __restrict__ winList,
    int* __restrict__ winCnt)
{
    const int b    = blockIdx.x;
    const int t    = threadIdx.x;
    const int lane = t & 63;
    const int wid  = t >> 6;
    __shared__ unsigned red[17];
    __shared__ unsigned wsum[16];

    float sv[16];
    unsigned bits[16];
    const float4* sp = (const float4*)(scores + (size_t)b * N_TOK + t * 16);
#pragma unroll
    for (int j = 0; j < 4; ++j) {
        const float4 v = sp[j];
        sv[j * 4 + 0] = v.x; sv[j * 4 + 1] = v.y;
        sv[j * 4 + 2] = v.z; sv[j * 4 + 3] = v.w;
    }
#pragma unroll
    for (int j = 0; j < 16; ++j) bits[j] = __float_as_uint(sv[j]);

    auto countGE = [&](unsigned v) -> unsigned {
        unsigned c = 0;
#pragma unroll
        for (int j = 0; j < 16; ++j) c += (bits[j] >= v) ? 1u : 0u;
        c += __shfl_xor(c, 32); c += __shfl_xor(c, 16); c += __shfl_xor(c, 8);
        c += __shfl_xor(c, 4);  c += __shfl_xor(c, 2);  c += __shfl_xor(c, 1);
        if (lane == 0) red[wid] = c;
        __syncthreads();
        if (wid == 0) {
            unsigned s = (lane < 16) ? red[lane] : 0u;
            s += __shfl_xor(s, 8); s += __shfl_xor(s, 4);
            s += __shfl_xor(s, 2); s += __shfl_xor(s, 1);
            if (lane == 0) red[16] = s;
        }
        __syncthreads();
        return red[16];
    };

    unsigned lo = 0u, hi = 0x40000000u;
    while (hi - lo > 1u) {
        const unsigned mid = (lo + hi) >> 1;
        if (countGE(mid) >= KEEP) lo = mid; else hi = mid;
    }
    const float sT = __uint_as_float(lo);

    int cnt = 0;
    bool inw[16];
#pragma unroll
    for (int j = 0; j < 16; ++j) {
        inw[j] = fabsf(sv[j] - sT) <= DELTA;
        cnt += inw[j] ? 1 : 0;
    }
    unsigned inc = (unsigned)cnt;
#pragma unroll
    for (int off = 1; off < 64; off <<= 1) {
        const unsigned n = __shfl_up(inc, off);
        if (lane >= off) inc += n;
    }
    const unsigned excl = inc - (unsigned)cnt;
    if (lane == 63) wsum[wid] = inc;
    __syncthreads();
    if (t == 0) {
        unsigned s = 0;
        for (int w = 0; w < 16; ++w) { const unsigned tmp = wsum[w]; wsum[w] = s; s += tmp; }
        winCnt[b] = (int)(s > WCAP ? WCAP : s);
    }
    __syncthreads();
    unsigned pos = wsum[wid] + excl;
#pragma unroll
    for (int j = 0; j < 16; ++j) {
        if (inw[j]) {
            if (pos < WCAP) winList[b * WCAP + pos] = t * 16 + j;
            ++pos;
        }
    }
}

// ---------------------------------------------------------------------------
// fix2: exact f32 recompute of windowed rows, 8 rows/group, 1024 threads,
// k-dim split over 4 thread-quads. Grid-stride over groups.
// ---------------------------------------------------------------------------
__global__ __launch_bounds__(1024) void fix2_kernel(
    const float* __restrict__ x, const float* __restrict__ W1,
    const float* __restrict__ b1, const float* __restrict__ W2,
    const float* __restrict__ b2, float* __restrict__ scores,
    const int* __restrict__ winList, const int* __restrict__ winCnt)
{
    __shared__ float xrT[1024][8];
    __shared__ float part[4][8][256];
    __shared__ int rows[8];

    const int t = threadIdx.x;
    int c[4], cum[5];
    cum[0] = 0;
    for (int b = 0; b < 4; ++b) {
        int cc = winCnt[b];
        if (cc > WCAP) cc = WCAP;
        if (cc < 0) cc = 0;
        c[b] = cc;
        cum[b + 1] = cum[b] + ((cc + 7) >> 3);
    }
    for (int g = blockIdx.x; g < cum[4]; g += gridDim.x) {
        int b = 0;
        while (g >= cum[b + 1]) ++b;
        const int gi   = g - cum[b];
        const int nval = min(8, c[b] - gi * 8);
        if (t < 8)
            rows[t] = winList[b * WCAP + gi * 8 + (t < nval ? t : 0)];
        __syncthreads();
        {
            const int r = t >> 7, c0 = (t & 127) * 8;
            const float* xp = x + ((size_t)b * N_TOK + rows[r]) * DIM + c0;
            const float4 a = ((const float4*)xp)[0], bq = ((const float4*)xp)[1];
            xrT[c0 + 0][r] = a.x;  xrT[c0 + 1][r] = a.y;
            xrT[c0 + 2][r] = a.z;  xrT[c0 + 3][r] = a.w;
            xrT[c0 + 4][r] = bq.x; xrT[c0 + 5][r] = bq.y;
            xrT[c0 + 6][r] = bq.z; xrT[c0 + 7][r] = bq.w;
        }
        __syncthreads();
        const int h = t & 255, q = t >> 8;
        float a8[8];
#pragma unroll
        for (int r = 0; r < 8; ++r) a8[r] = 0.f;
        const int k0 = q * 256;
        for (int k = 0; k < 256; ++k) {
            const float wv = W1[(size_t)(k0 + k) * HID + h];
            const float4 xa = *(const float4*)&xrT[k0 + k][0];
            const float4 xb = *(const float4*)&xrT[k0 + k][4];
            a8[0] = fmaf(xa.x, wv, a8[0]); a8[1] = fmaf(xa.y, wv, a8[1]);
            a8[2] = fmaf(xa.z, wv, a8[2]); a8[3] = fmaf(xa.w, wv, a8[3]);
            a8[4] = fmaf(xb.x, wv, a8[4]); a8[5] = fmaf(xb.y, wv, a8[5]);
            a8[6] = fmaf(xb.z, wv, a8[6]); a8[7] = fmaf(xb.w, wv, a8[7]);
        }
#pragma unroll
        for (int r = 0; r < 8; ++r) part[q][r][h] = a8[r];
        __syncthreads();
        const int wid = t >> 6, lane = t & 63;
        if (wid < 8) {
            const int r = wid;
            float v = 0.f;
#pragma unroll
            for (int i = 0; i < 4; ++i) {
                const int hc = i * 64 + lane;
                float hv = (part[0][r][hc] + part[1][r][hc]) + (part[2][r][hc] + part[3][r][hc]);
                hv = fmaxf(hv + b1[hc], 0.f);
                v = fmaf(hv, W2[hc], v);
            }
            v += __shfl_xor(v, 32); v += __shfl_xor(v, 16); v += __shfl_xor(v, 8);
            v += __shfl_xor(v, 4);  v += __shfl_xor(v, 2);  v += __shfl_xor(v, 1);
            if (lane == 0 && r < nval)
                scores[(size_t)b * N_TOK + rows[r]] = 1.f / (1.f + expf(-(v + b2[0])));
        }
        __syncthreads();
    }
}

// ---------------------------------------------------------------------------
// select: exact top-k per batch on corrected scores; wave-parallel reduce.
// ---------------------------------------------------------------------------
__global__ __launch_bounds__(1024) void select_kernel(
    const float* __restrict__ scores, int* __restrict__ idxList)
{
    const int b    = blockIdx.x;
    const int t    = threadIdx.x;
    const int lane = t & 63;
    const int wid  = t >> 6;
    __shared__ unsigned red[17];

    unsigned bits[16];
    const float4* sp = (const float4*)(scores + (size_t)b * N_TOK + t * 16);
#pragma unroll
    for (int j = 0; j < 4; ++j) {
        const float4 v = sp[j];
        bits[j * 4 + 0] = __float_as_uint(v.x);
        bits[j * 4 + 1] = __float_as_uint(v.y);
        bits[j * 4 + 2] = __float_as_uint(v.z);
        bits[j * 4 + 3] = __float_as_uint(v.w);
    }

    auto countGE = [&](unsigned v) -> unsigned {
        unsigned c = 0;
#pragma unroll
        for (int j = 0; j < 16; ++j) c += (bits[j] >= v) ? 1u : 0u;
        c += __shfl_xor(c, 32); c += __shfl_xor(c, 16); c += __shfl_xor(c, 8);
        c += __shfl_xor(c, 4);  c += __shfl_xor(c, 2);  c += __shfl_xor(c, 1);
        if (lane == 0) red[wid] = c;
        __syncthreads();
        if (wid == 0) {
            unsigned s = (lane < 16) ? red[lane] : 0u;
            s += __shfl_xor(s, 8); s += __shfl_xor(s, 4);
            s += __shfl_xor(s, 2); s += __shfl_xor(s, 1);
            if (lane == 0) red[16] = s;
        }
        __syncthreads();
        return red[16];
    };

    unsigned lo = 0u, hi = 0x40000000u;
    while (hi - lo > 1u) {
        const unsigned mid = (lo + hi) >> 1;
        if (countGE(mid) >= KEEP) lo = mid; else hi = mid;
    }
    const unsigned T    = lo;
    const unsigned cGT  = countGE(T + 1u);
    const unsigned need = KEEP - cGT;

    unsigned pre[16];
    unsigned run = 0;
#pragma unroll
    for (int j = 0; j < 16; ++j) {
        pre[j] = run;
        const unsigned gt = (bits[j] > T) ? 1u : 0u;
        const unsigned eq = (bits[j] == T) ? 1u : 0u;
        run += gt | (eq << 16);
    }
    unsigned inc = run;
#pragma unroll
    for (int off = 1; off < 64; off <<= 1) {
        const unsigned n = __shfl_up(inc, off);
        if (lane >= off) inc += n;
    }
    const unsigned waveExcl = inc - run;
    if (lane == 63) red[wid] = inc;
    __syncthreads();
    if (t == 0) {
        unsigned s = 0;
        for (int w = 0; w < 16; ++w) { const unsigned tmp = red[w]; red[w] = s; s += tmp; }
    }
    __syncthreads();
    const unsigned base = red[wid] + waveExcl;

#pragma unroll
    for (int j = 0; j < 16; ++j) {
        const unsigned pe    = base + pre[j];
        const unsigned tieR  = pe >> 16;
        const unsigned posGT = pe & 0xFFFFu;
        const bool gt = bits[j] > T;
        const bool eq = bits[j] == T;
        if (gt || (eq && tieR < need)) {
            const unsigned pos = posGT + (tieR < need ? tieR : need);
            idxList[(size_t)b * KEEP + pos] = t * 16 + j;
        }
    }
}

// ---------------------------------------------------------------------------
// gather: weighted gather, float4 (HBM-bound, near roofline).
// ---------------------------------------------------------------------------
__global__ __launch_bounds__(256) void gather_kernel(
    const float* __restrict__ x, const float* __restrict__ scores,
    const int* __restrict__ idxList, float* __restrict__ out)
{
    const int t = threadIdx.x;
#pragma unroll
    for (int q = 0; q < 4; ++q) {
        const int orow = blockIdx.x * 4 + q;
        const int b    = orow / KEEP;
        const int idx  = idxList[orow];
        const float s  = scores[(size_t)b * N_TOK + idx];
        const float4 v = *(const float4*)(x + (((size_t)b * N_TOK + idx) << 10) + t * 4);
        float4 o;
        o.x = v.x * s; o.y = v.y * s; o.z = v.z * s; o.w = v.w * s;
        *(float4*)(out + ((size_t)orow << 10) + t * 4) = o;
    }
}

// ---------------------------------------------------------------------------
// loss: -mean(|s-0.5|) over 256 block partials.
// ---------------------------------------------------------------------------
__global__ __launch_bounds__(256) void loss_kernel(
    const float* __restrict__ partials, float* __restrict__ outLoss)
{
    __shared__ float red[256];
    const int t = threadIdx.x;
    red[t] = partials[t];
    __syncthreads();
    for (int off = 128; off > 0; off >>= 1) {
        if (t < off) red[t] += red[t + off];
        __syncthreads();
    }
    if (t == 0) outLoss[0] = -(red[0] / (float)MROWS);
}

extern "C" void kernel_launch(void* const* d_in, const int* in_sizes, int n_in,
                              void* d_out, int out_size, void* d_ws, size_t ws_size,
                              hipStream_t stream)
{
    const float* x  = (const float*)d_in[0];
    const float* W1 = (const float*)d_in[1];
    const float* b1 = (const float*)d_in[2];
    const float* W2 = (const float*)d_in[3];
    const float* b2 = (const float*)d_in[4];
    float* out = (float*)d_out;

    char* ws = (char*)d_ws;
    float* scores   = (float*)ws;                 // 262144 B
    float* partials = (float*)(ws + 262144);      // 4096 B (256 used)
    int*   idxList  = (int*)(ws + 266240);        // 183488 B
    ushort* Wpk     = (ushort*)(ws + 458752);     // 524288 B
    int*   winList  = (int*)(ws + 983040);        // 65536 B
    int*   winCnt   = (int*)(ws + 1048576);       // 16 B

    prep_kernel<<<16, 256, 0, stream>>>(W1, Wpk);
    score_mfma<<<MROWS / BM, 512, 0, stream>>>(x, Wpk, b1, W2, b2, scores, partials);
    loss_kernel<<<1, 256, 0, stream>>>(partials, out + (size_t)BATCH * KEEP * DIM);
    fixfind_kernel<<<BATCH, 1024, 0, stream>>>(scores, winList, winCnt);
    fix2_kernel<<<256, 1024, 0, stream>>>(x, W1, b1, W2, b2, scores, winList, winCnt);
    select_kernel<<<BATCH, 1024, 0, stream>>>(scores, idxList);
    gather_kernel<<<KEEP, 256, 0, stream>>>(x, scores, idxList, out);
}

// Round 12
// 203.932 us; speedup vs baseline: 1.5619x; 1.1737x over previous
//
#include <hip/hip_runtime.h>
#include <hip/hip_bf16.h>
#include <math.h>

#define N_TOK 16384
#define BATCH 4
#define DIM   1024
#define HID   256
#define KEEP  11468            // int(16384 * 0.7)
#define MROWS 65536
#define BK    32
#define NKT   (DIM / BK)       // 32 K-iters
#define DELTA 6e-3f            // exact-recompute window around approx cut
#define WCAP  4096             // max window rows per batch
#define AP    40               // A row pitch in ushorts (80B: 2-way bank alias = free)
#define ASLOT (128 * AP)       // 5120 ushorts per A slot
#define BSLOT (16 * 512)       // 8192 ushorts per B slot

typedef __attribute__((ext_vector_type(8))) short bf16x8;
typedef __attribute__((ext_vector_type(4))) float f32x4;

__device__ inline unsigned bf16_rne(float f) {
    unsigned u = __float_as_uint(f);
    return (u + 0x7FFFu + ((u >> 16) & 1u)) >> 16;
}

#define GLDS16(gp, lp) __builtin_amdgcn_global_load_lds( \
    (const __attribute__((address_space(1))) void*)(gp), \
    (__attribute__((address_space(3))) void*)(lp), 16, 0, 0)

// ---------------------------------------------------------------------------
// radix_thresh: exact top-k threshold over 16384 positive-float bit patterns
// held 16/thread in a 1024-thread block. 3-level radix (16384/256/256
// buckets), suffix-scanned histograms. Returns T = k-th largest bits value
// (attained) and cGT = count of bits > T. Deterministic.
// hist: LDS, 16385 entries. aux: LDS, >= 24 entries.
// ---------------------------------------------------------------------------
__device__ __forceinline__ void radix_thresh(
    const unsigned bits[16], const int t, const int lane, const int wid,
    unsigned* hist, unsigned* aux, unsigned& T, unsigned& cGT)
{
    // ---- level 1: buckets = bits >> 16 (all scores in [0,1] -> < 16257) ----
#pragma unroll
    for (int i = 0; i < 16; ++i) hist[t * 16 + i] = 0u;
    if (t == 0) hist[16384] = 0u;
    __syncthreads();
#pragma unroll
    for (int j = 0; j < 16; ++j) atomicAdd(&hist[bits[j] >> 16], 1u);
    __syncthreads();
    unsigned loc[16];
    unsigned s = 0;
#pragma unroll
    for (int i = 15; i >= 0; --i) { s += hist[t * 16 + i]; loc[i] = s; }
    unsigned inc = s;
#pragma unroll
    for (int off = 1; off < 64; off <<= 1) {
        const unsigned n = __shfl_down(inc, off);
        if (lane + off < 64) inc += n;
    }
    if (lane == 0) aux[wid] = inc;     // wave suffix totals
    __syncthreads();
    if (t == 0) {
        unsigned run = 0;
        for (int w = 15; w >= 0; --w) { const unsigned tmp = aux[w]; aux[w] = run; run += tmp; }
    }
    __syncthreads();
    const unsigned above = aux[wid] + (inc - s);
#pragma unroll
    for (int i = 0; i < 16; ++i) hist[t * 16 + i] = loc[i] + above;   // S1 suffix
    __syncthreads();
#pragma unroll
    for (int i = 0; i < 16; ++i) {
        const int B = t * 16 + i;
        if (hist[B] >= KEEP && hist[B + 1] < KEEP) {
            aux[16] = (unsigned)B;
            aux[17] = hist[B + 1];     // base1 = count in strictly-higher buckets
        }
    }
    __syncthreads();
    const unsigned B1 = aux[16];
    const unsigned base1 = aux[17];
    __syncthreads();

    // ---- level 2: buckets = (bits >> 8) & 0xFF among bucket B1 ----
    if (t < 257) hist[t] = 0u;
    __syncthreads();
#pragma unroll
    for (int j = 0; j < 16; ++j)
        if ((bits[j] >> 16) == B1) atomicAdd(&hist[(bits[j] >> 8) & 0xFFu], 1u);
    __syncthreads();
    if (wid == 0) {
        unsigned l4[4];
        unsigned ss = 0;
#pragma unroll
        for (int i = 3; i >= 0; --i) { ss += hist[lane * 4 + i]; l4[i] = ss; }
        unsigned inc2 = ss;
#pragma unroll
        for (int off = 1; off < 64; off <<= 1) {
            const unsigned n = __shfl_down(inc2, off);
            if (lane + off < 64) inc2 += n;
        }
        const unsigned abv = inc2 - ss;
#pragma unroll
        for (int i = 0; i < 4; ++i) hist[lane * 4 + i] = l4[i] + abv;
        if (lane == 0) hist[256] = 0u;
    }
    __syncthreads();
    if (t < 256) {
        if (base1 + hist[t] >= KEEP && base1 + hist[t + 1] < KEEP) {
            aux[18] = (unsigned)t;
            aux[19] = base1 + hist[t + 1];
        }
    }
    __syncthreads();
    const unsigned b2 = aux[18];
    const unsigned base2 = aux[19];
    __syncthreads();

    // ---- level 3: buckets = bits & 0xFF among (B1, b2) ----
    const unsigned pfx = (B1 << 8) | b2;
    if (t < 257) hist[t] = 0u;
    __syncthreads();
#pragma unroll
    for (int j = 0; j < 16; ++j)
        if ((bits[j] >> 8) == pfx) atomicAdd(&hist[bits[j] & 0xFFu], 1u);
    __syncthreads();
    if (wid == 0) {
        unsigned l4[4];
        unsigned ss = 0;
#pragma unroll
        for (int i = 3; i >= 0; --i) { ss += hist[lane * 4 + i]; l4[i] = ss; }
        unsigned inc2 = ss;
#pragma unroll
        for (int off = 1; off < 64; off <<= 1) {
            const unsigned n = __shfl_down(inc2, off);
            if (lane + off < 64) inc2 += n;
        }
        const unsigned abv = inc2 - ss;
#pragma unroll
        for (int i = 0; i < 4; ++i) hist[lane * 4 + i] = l4[i] + abv;
        if (lane == 0) hist[256] = 0u;
    }
    __syncthreads();
    if (t < 256) {
        if (base2 + hist[t] >= KEEP && base2 + hist[t + 1] < KEEP) {
            aux[20] = (unsigned)t;
            aux[21] = base2 + hist[t + 1];
        }
    }
    __syncthreads();
    T   = (B1 << 16) | (b2 << 8) | aux[20];
    cGT = aux[21];
    __syncthreads();
}

// ---------------------------------------------------------------------------
// prep: pack W1 (f32 [k][h]) into MFMA-B-fragment lines, bf16:
// line L = K32*16 + hg; within line: lane&15 = h offset, (lane>>4)*8+j = k.
// ---------------------------------------------------------------------------
__global__ __launch_bounds__(256) void prep_kernel(
    const float* __restrict__ W1, ushort* __restrict__ Wpk)
{
    const int kt = blockIdx.x;   // 0..15
    for (int idx = threadIdx.x; idx < 2048; idx += 256) {
        const int lane = idx & 63;
        const int g    = idx >> 6;        // 0..31
        const int h    = (g & 15) * 16 + (lane & 15);
        const int kb   = kt * 64 + (g >> 4) * 32 + (lane >> 4) * 8;
        ushort v[8];
#pragma unroll
        for (int j = 0; j < 8; ++j)
            v[j] = (ushort)bf16_rne(W1[(size_t)(kb + j) * HID + h]);
        *(uint4*)(Wpk + ((size_t)(kt * 32 + g) * 64 + lane) * 8) = *(uint4*)v;
    }
}

// ---------------------------------------------------------------------------
// score: best-measured variant (r6, 227.7 total): 3-slot circular LDS,
// counted vmcnt (never 0 in main loop), raw s_barrier. 512 thr = 8 waves,
// tile 128 x 256, BK=32.
// ---------------------------------------------------------------------------
__global__ __launch_bounds__(512, 4) void score_mfma(
    const float* __restrict__ x, const ushort* __restrict__ Wpk,
    const float* __restrict__ b1, const float* __restrict__ W2,
    const float* __restrict__ b2, float* __restrict__ scores,
    float* __restrict__ partials)
{
    __shared__ ushort AsAll[3 * ASLOT];
    __shared__ ushort BsAll[3 * BSLOT];

    const int t    = threadIdx.x;
    const int lane = t & 63;
    const int w    = t >> 6;         // 0..7
    const int wr   = w >> 2;         // 0..1  (64 rows each)
    const int wc   = w & 3;          // 0..3  (64 cols each)
    const int l15  = lane & 15;
    const int lk   = lane >> 4;
    const size_t row0 = (size_t)blockIdx.x * 128;

    const int arow = t >> 2;         // 0..127
    const int aq   = t & 3;          // 8-float chunk of 32-k slice
    const float* xbase = x + (row0 + arow) * DIM + aq * 8;

    f32x4 acc[4][4];
#pragma unroll
    for (int rf = 0; rf < 4; ++rf)
#pragma unroll
        for (int cf = 0; cf < 4; ++cf) acc[rf][cf] = (f32x4){0.f, 0.f, 0.f, 0.f};

    float4 p0a, p0b, p1a, p1b;       // two A prefetch register sets

#define ISSUEA(KT, PA, PB) { \
        const float4* xp = (const float4*)(xbase + (size_t)(KT) * BK); \
        PA = xp[0]; PB = xp[1]; }
#define CONVA(PA, PB, SLOT) { \
        ushort hb[8]; \
        hb[0] = (ushort)bf16_rne(PA.x); hb[1] = (ushort)bf16_rne(PA.y); \
        hb[2] = (ushort)bf16_rne(PA.z); hb[3] = (ushort)bf16_rne(PA.w); \
        hb[4] = (ushort)bf16_rne(PB.x); hb[5] = (ushort)bf16_rne(PB.y); \
        hb[6] = (ushort)bf16_rne(PB.z); hb[7] = (ushort)bf16_rne(PB.w); \
        *(uint4*)&AsAll[(SLOT) * ASLOT + arow * AP + aq * 8] = *(uint4*)&hb[0]; }
#define ISSUEB(KT, SLOT) { \
        _Pragma("unroll") \
        for (int i = 0; i < 2; ++i) { \
            const int g_ = w * 2 + i; \
            GLDS16(Wpk + (((size_t)(KT) * 16 + g_) * 64 + lane) * 8, \
                   &BsAll[(SLOT) * BSLOT + g_ * 512 + lane * 8]); \
        } }
#define COMPUTE(SLOT) { \
        bf16x8 Af[4]; \
        _Pragma("unroll") \
        for (int rf = 0; rf < 4; ++rf) { \
            const int row = wr * 64 + rf * 16 + l15; \
            Af[rf] = *(const bf16x8*)&AsAll[(SLOT) * ASLOT + row * AP + lk * 8]; \
        } \
        _Pragma("unroll") \
        for (int cf = 0; cf < 4; ++cf) { \
            const bf16x8 Bf = *(const bf16x8*)&BsAll[(SLOT) * BSLOT + (wc * 4 + cf) * 512 + lane * 8]; \
            acc[0][cf] = __builtin_amdgcn_mfma_f32_16x16x32_bf16(Af[0], Bf, acc[0][cf], 0, 0, 0); \
            acc[1][cf] = __builtin_amdgcn_mfma_f32_16x16x32_bf16(Af[1], Bf, acc[1][cf], 0, 0, 0); \
            acc[2][cf] = __builtin_amdgcn_mfma_f32_16x16x32_bf16(Af[2], Bf, acc[2][cf], 0, 0, 0); \
            acc[3][cf] = __builtin_amdgcn_mfma_f32_16x16x32_bf16(Af[3], Bf, acc[3][cf], 0, 0, 0); \
        } }

    // ---- prologue
    ISSUEB(0, 0);
    ISSUEA(0, p0a, p0b);
    ISSUEA(1, p1a, p1b);
    CONVA(p0a, p0b, 0);
    asm volatile("s_waitcnt lgkmcnt(0)" ::: "memory");
    __builtin_amdgcn_s_barrier();
    __builtin_amdgcn_sched_barrier(0);

    for (int kt = 0; kt < NKT; ++kt) {
        if (kt < NKT - 2) {
            if ((kt & 1) == 0) { ISSUEA(kt + 2, p0a, p0b); }
            else               { ISSUEA(kt + 2, p1a, p1b); }
        }
        if (kt < NKT - 1) {
            const int s1 = (kt + 1) % 3;
            ISSUEB(kt + 1, s1);
            if ((kt & 1) == 0) { CONVA(p1a, p1b, s1); }
            else               { CONVA(p0a, p0b, s1); }
        }
        if (kt < NKT - 2)       asm volatile("s_waitcnt vmcnt(4)" ::: "memory");
        else if (kt == NKT - 2) asm volatile("s_waitcnt vmcnt(2)" ::: "memory");
        else                    asm volatile("s_waitcnt vmcnt(0)" ::: "memory");
        asm volatile("s_waitcnt lgkmcnt(0)" ::: "memory");
        __builtin_amdgcn_s_barrier();
        __builtin_amdgcn_sched_barrier(0);
        COMPUTE(kt % 3);
    }

    // ---- epilogue (zb/rd aliased onto Bs slot 0)
    float* zb = (float*)&BsAll[0];        // [128][4]
    float* rd = (float*)&BsAll[1024];     // [128]
    float b1r[4], w2r[4];
#pragma unroll
    for (int cf = 0; cf < 4; ++cf) {
        const int col = wc * 64 + cf * 16 + l15;
        b1r[cf] = b1[col];
        w2r[cf] = W2[col];
    }
#pragma unroll
    for (int rf = 0; rf < 4; ++rf) {
#pragma unroll
        for (int j = 0; j < 4; ++j) {
            float z = 0.f;
#pragma unroll
            for (int cf = 0; cf < 4; ++cf)
                z = fmaf(fmaxf(acc[rf][cf][j] + b1r[cf], 0.f), w2r[cf], z);
            z += __shfl_xor(z, 1);
            z += __shfl_xor(z, 2);
            z += __shfl_xor(z, 4);
            z += __shfl_xor(z, 8);
            if (l15 == 0) zb[(wr * 64 + rf * 16 + lk * 4 + j) * 4 + wc] = z;
        }
    }
    __syncthreads();
    if (t < 128) {
        const float z = (zb[t * 4 + 0] + zb[t * 4 + 1]) + (zb[t * 4 + 2] + zb[t * 4 + 3]) + b2[0];
        const float s = 1.f / (1.f + expf(-z));
        scores[row0 + t] = s;
        rd[t] = fabsf(s - 0.5f);
    }
    __syncthreads();
    for (int off = 64; off > 0; off >>= 1) {
        if (t < off) rd[t] += rd[t + off];
        __syncthreads();
    }
    if (t == 0) partials[blockIdx.x] = rd[0];
}

// ---------------------------------------------------------------------------
// fixfind: radix-select approx threshold, emit rows within +-DELTA.
// ---------------------------------------------------------------------------
__global__ __launch_bounds__(1024) void fixfind_kernel(
    const float* __restrict__ scores, int* __restrict__ winList,
    int* __restrict__ winCnt)
{
    const int b    = blockIdx.x;
    const int t    = threadIdx.x;
    const int lane = t & 63;
    const int wid  = t >> 6;
    __shared__ unsigned hist[16385];
    __shared__ unsigned aux[24];
    __shared__ unsigned wsum[16];

    float sv[16];
    unsigned bits[16];
    const float4* sp = (const float4*)(scores + (size_t)b * N_TOK + t * 16);
#pragma unroll
    for (int j = 0; j < 4; ++j) {
        const float4 v = sp[j];
        sv[j * 4 + 0] = v.x; sv[j * 4 + 1] = v.y;
        sv[j * 4 + 2] = v.z; sv[j * 4 + 3] = v.w;
    }
#pragma unroll
    for (int j = 0; j < 16; ++j) bits[j] = __float_as_uint(sv[j]);

    unsigned T, cGT;
    radix_thresh(bits, t, lane, wid, hist, aux, T, cGT);
    const float sT = __uint_as_float(T);

    int cnt = 0;
    bool inw[16];
#pragma unroll
    for (int j = 0; j < 16; ++j) {
        inw[j] = fabsf(sv[j] - sT) <= DELTA;
        cnt += inw[j] ? 1 : 0;
    }
    unsigned inc = (unsigned)cnt;
#pragma unroll
    for (int off = 1; off < 64; off <<= 1) {
        const unsigned n = __shfl_up(inc, off);
        if (lane >= off) inc += n;
    }
    const unsigned excl = inc - (unsigned)cnt;
    if (lane == 63) wsum[wid] = inc;
    __syncthreads();
    if (t == 0) {
        unsigned s = 0;
        for (int w = 0; w < 16; ++w) { const unsigned tmp = wsum[w]; wsum[w] = s; s += tmp; }
        winCnt[b] = (int)(s > WCAP ? WCAP : s);
    }
    __syncthreads();
    unsigned pos = wsum[wid] + excl;
#pragma unroll
    for (int j = 0; j < 16; ++j) {
        if (inw[j]) {
            if (pos < WCAP) winList[b * WCAP + pos] = t * 16 + j;
            ++pos;
        }
    }
}

// ---------------------------------------------------------------------------
// fix2: exact f32 recompute of windowed rows, 8 rows/group, 1024 threads.
// ---------------------------------------------------------------------------
__global__ __launch_bounds__(1024) void fix2_kernel(
    const float* __restrict__ x, const float* __restrict__ W1,
    const float* __restrict__ b1, const float* __restrict__ W2,
    const float* __restrict__ b2, float* __restrict__ scores,
    const int* __restrict__ winList, const int* __restrict__ winCnt)
{
    __shared__ float xrT[1024][8];
    __shared__ float part[4][8][256];
    __shared__ int rows[8];

    const int t = threadIdx.x;
    int c[4], cum[5];
    cum[0] = 0;
    for (int b = 0; b < 4; ++b) {
        int cc = winCnt[b];
        if (cc > WCAP) cc = WCAP;
        if (cc < 0) cc = 0;
        c[b] = cc;
        cum[b + 1] = cum[b] + ((cc + 7) >> 3);
    }
    for (int g = blockIdx.x; g < cum[4]; g += gridDim.x) {
        int b = 0;
        while (g >= cum[b + 1]) ++b;
        const int gi   = g - cum[b];
        const int nval = min(8, c[b] - gi * 8);
        if (t < 8)
            rows[t] = winList[b * WCAP + gi * 8 + (t < nval ? t : 0)];
        __syncthreads();
        {
            const int r = t >> 7, c0 = (t & 127) * 8;
            const float* xp = x + ((size_t)b * N_TOK + rows[r]) * DIM + c0;
            const float4 a = ((const float4*)xp)[0], bq = ((const float4*)xp)[1];
            xrT[c0 + 0][r] = a.x;  xrT[c0 + 1][r] = a.y;
            xrT[c0 + 2][r] = a.z;  xrT[c0 + 3][r] = a.w;
            xrT[c0 + 4][r] = bq.x; xrT[c0 + 5][r] = bq.y;
            xrT[c0 + 6][r] = bq.z; xrT[c0 + 7][r] = bq.w;
        }
        __syncthreads();
        const int h = t & 255, q = t >> 8;
        float a8[8];
#pragma unroll
        for (int r = 0; r < 8; ++r) a8[r] = 0.f;
        const int k0 = q * 256;
        for (int k = 0; k < 256; ++k) {
            const float wv = W1[(size_t)(k0 + k) * HID + h];
            const float4 xa = *(const float4*)&xrT[k0 + k][0];
            const float4 xb = *(const float4*)&xrT[k0 + k][4];
            a8[0] = fmaf(xa.x, wv, a8[0]); a8[1] = fmaf(xa.y, wv, a8[1]);
            a8[2] = fmaf(xa.z, wv, a8[2]); a8[3] = fmaf(xa.w, wv, a8[3]);
            a8[4] = fmaf(xb.x, wv, a8[4]); a8[5] = fmaf(xb.y, wv, a8[5]);
            a8[6] = fmaf(xb.z, wv, a8[6]); a8[7] = fmaf(xb.w, wv, a8[7]);
        }
#pragma unroll
        for (int r = 0; r < 8; ++r) part[q][r][h] = a8[r];
        __syncthreads();
        const int wid = t >> 6, lane = t & 63;
        if (wid < 8) {
            const int r = wid;
            float v = 0.f;
#pragma unroll
            for (int i = 0; i < 4; ++i) {
                const int hc = i * 64 + lane;
                float hv = (part[0][r][hc] + part[1][r][hc]) + (part[2][r][hc] + part[3][r][hc]);
                hv = fmaxf(hv + b1[hc], 0.f);
                v = fmaf(hv, W2[hc], v);
            }
            v += __shfl_xor(v, 32); v += __shfl_xor(v, 16); v += __shfl_xor(v, 8);
            v += __shfl_xor(v, 4);  v += __shfl_xor(v, 2);  v += __shfl_xor(v, 1);
            if (lane == 0 && r < nval)
                scores[(size_t)b * N_TOK + rows[r]] = 1.f / (1.f + expf(-(v + b2[0])));
        }
        __syncthreads();
    }
}

// ---------------------------------------------------------------------------
// select: radix-select exact top-k per batch on corrected scores; emission
// (packed gt/eq prefix scan, tie-break lowest index) verbatim from r1-r11.
// ---------------------------------------------------------------------------
__global__ __launch_bounds__(1024) void select_kernel(
    const float* __restrict__ scores, int* __restrict__ idxList)
{
    const int b    = blockIdx.x;
    const int t    = threadIdx.x;
    const int lane = t & 63;
    const int wid  = t >> 6;
    __shared__ unsigned hist[16385];
    __shared__ unsigned aux[24];
    __shared__ unsigned wsum[16];

    unsigned bits[16];
    const float4* sp = (const float4*)(scores + (size_t)b * N_TOK + t * 16);
#pragma unroll
    for (int j = 0; j < 4; ++j) {
        const float4 v = sp[j];
        bits[j * 4 + 0] = __float_as_uint(v.x);
        bits[j * 4 + 1] = __float_as_uint(v.y);
        bits[j * 4 + 2] = __float_as_uint(v.z);
        bits[j * 4 + 3] = __float_as_uint(v.w);
    }

    unsigned T, cGT;
    radix_thresh(bits, t, lane, wid, hist, aux, T, cGT);
    const unsigned need = KEEP - cGT;

    unsigned pre[16];
    unsigned run = 0;
#pragma unroll
    for (int j = 0; j < 16; ++j) {
        pre[j] = run;
        const unsigned gt = (bits[j] > T) ? 1u : 0u;
        const unsigned eq = (bits[j] == T) ? 1u : 0u;
        run += gt | (eq << 16);
    }
    unsigned inc = run;
#pragma unroll
    for (int off = 1; off < 64; off <<= 1) {
        const unsigned n = __shfl_up(inc, off);
        if (lane >= off) inc += n;
    }
    const unsigned waveExcl = inc - run;
    if (lane == 63) wsum[wid] = inc;
    __syncthreads();
    if (t == 0) {
        unsigned s = 0;
        for (int w = 0; w < 16; ++w) { const unsigned tmp = wsum[w]; wsum[w] = s; s += tmp; }
    }
    __syncthreads();
    const unsigned base = wsum[wid] + waveExcl;

#pragma unroll
    for (int j = 0; j < 16; ++j) {
        const unsigned pe    = base + pre[j];
        const unsigned tieR  = pe >> 16;
        const unsigned posGT = pe & 0xFFFFu;
        const bool gt = bits[j] > T;
        const bool eq = bits[j] == T;
        if (gt || (eq && tieR < need)) {
            const unsigned pos = posGT + (tieR < need ? tieR : need);
            idxList[(size_t)b * KEEP + pos] = t * 16 + j;
        }
    }
}

// ---------------------------------------------------------------------------
// gather: weighted gather, float4 (HBM-bound, near roofline).
// ---------------------------------------------------------------------------
__global__ __launch_bounds__(256) void gather_kernel(
    const float* __restrict__ x, const float* __restrict__ scores,
    const int* __restrict__ idxList, float* __restrict__ out)
{
    const int t = threadIdx.x;
#pragma unroll
    for (int q = 0; q < 4; ++q) {
        const int orow = blockIdx.x * 4 + q;
        const int b    = orow / KEEP;
        const int idx  = idxList[orow];
        const float s  = scores[(size_t)b * N_TOK + idx];
        const float4 v = *(const float4*)(x + (((size_t)b * N_TOK + idx) << 10) + t * 4);
        float4 o;
        o.x = v.x * s; o.y = v.y * s; o.z = v.z * s; o.w = v.w * s;
        *(float4*)(out + ((size_t)orow << 10) + t * 4) = o;
    }
}

// ---------------------------------------------------------------------------
// loss: -mean(|s-0.5|) over 512 block partials.
// ---------------------------------------------------------------------------
__global__ __launch_bounds__(256) void loss_kernel(
    const float* __restrict__ partials, float* __restrict__ outLoss)
{
    __shared__ float red[256];
    const int t = threadIdx.x;
    red[t] = partials[t] + partials[t + 256];
    __syncthreads();
    for (int off = 128; off > 0; off >>= 1) {
        if (t < off) red[t] += red[t + off];
        __syncthreads();
    }
    if (t == 0) outLoss[0] = -(red[0] / (float)MROWS);
}

extern "C" void kernel_launch(void* const* d_in, const int* in_sizes, int n_in,
                              void* d_out, int out_size, void* d_ws, size_t ws_size,
                              hipStream_t stream)
{
    const float* x  = (const float*)d_in[0];
    const float* W1 = (const float*)d_in[1];
    const float* b1 = (const float*)d_in[2];
    const float* W2 = (const float*)d_in[3];
    const float* b2 = (const float*)d_in[4];
    float* out = (float*)d_out;

    char* ws = (char*)d_ws;
    float* scores   = (float*)ws;                 // 262144 B
    float* partials = (float*)(ws + 262144);      // 4096 B (512 used)
    int*   idxList  = (int*)(ws + 266240);        // 183488 B
    ushort* Wpk     = (ushort*)(ws + 458752);     // 524288 B
    int*   winList  = (int*)(ws + 983040);        // 65536 B
    int*   winCnt   = (int*)(ws + 1048576);       // 16 B

    prep_kernel<<<16, 256, 0, stream>>>(W1, Wpk);
    score_mfma<<<MROWS / 128, 512, 0, stream>>>(x, Wpk, b1, W2, b2, scores, partials);
    loss_kernel<<<1, 256, 0, stream>>>(partials, out + (size_t)BATCH * KEEP * DIM);
    fixfind_kernel<<<BATCH, 1024, 0, stream>>>(scores, winList, winCnt);
    fix2_kernel<<<256, 1024, 0, stream>>>(x, W1, b1, W2, b2, scores, winList, winCnt);
    select_kernel<<<BATCH, 1024, 0, stream>>>(scores, idxList);
    gather_kernel<<<KEEP, 256, 0, stream>>>(x, scores, idxList, out);
}

// Round 13
// 199.006 us; speedup vs baseline: 1.6006x; 1.0248x over previous
//
#include <hip/hip_runtime.h>
#include <hip/hip_bf16.h>
#include <math.h>

#define N_TOK 16384
#define BATCH 4
#define DIM   1024
#define HID   256
#define KEEP  11468            // int(16384 * 0.7)
#define MROWS 65536
#define BK    32
#define NKT   (DIM / BK)       // 32 K-iters
#define DELTA 2.5e-3f          // exact-recompute window (10 sigma of bf16 score err)
#define WCAP  4096             // max window rows per batch
#define AP    40               // A row pitch in ushorts (80B: 2-way bank alias = free)
#define ASLOT (128 * AP)       // 5120 ushorts per A slot
#define BSLOT (16 * 512)       // 8192 ushorts per B slot

typedef __attribute__((ext_vector_type(8))) short bf16x8;
typedef __attribute__((ext_vector_type(4))) float f32x4;

__device__ inline unsigned bf16_rne(float f) {
    unsigned u = __float_as_uint(f);
    return (u + 0x7FFFu + ((u >> 16) & 1u)) >> 16;
}

#define GLDS16(gp, lp) __builtin_amdgcn_global_load_lds( \
    (const __attribute__((address_space(1))) void*)(gp), \
    (__attribute__((address_space(3))) void*)(lp), 16, 0, 0)

// ---------------------------------------------------------------------------
// radix_thresh: exact top-k threshold over 16384 positive-float bit patterns
// (16/thread, 1024-thread block). 3-level radix, suffix-scanned histograms.
// Returns T = k-th largest bits value and cGT = count of bits > T.
// ---------------------------------------------------------------------------
__device__ __forceinline__ void radix_thresh(
    const unsigned bits[16], const int t, const int lane, const int wid,
    unsigned* hist, unsigned* aux, unsigned& T, unsigned& cGT)
{
    // ---- level 1: buckets = bits >> 16 ----
#pragma unroll
    for (int i = 0; i < 16; ++i) hist[t * 16 + i] = 0u;
    if (t == 0) hist[16384] = 0u;
    __syncthreads();
#pragma unroll
    for (int j = 0; j < 16; ++j) atomicAdd(&hist[bits[j] >> 16], 1u);
    __syncthreads();
    unsigned loc[16];
    unsigned s = 0;
#pragma unroll
    for (int i = 15; i >= 0; --i) { s += hist[t * 16 + i]; loc[i] = s; }
    unsigned inc = s;
#pragma unroll
    for (int off = 1; off < 64; off <<= 1) {
        const unsigned n = __shfl_down(inc, off);
        if (lane + off < 64) inc += n;
    }
    if (lane == 0) aux[wid] = inc;     // wave suffix totals
    __syncthreads();
    if (t == 0) {
        unsigned run = 0;
        for (int w = 15; w >= 0; --w) { const unsigned tmp = aux[w]; aux[w] = run; run += tmp; }
    }
    __syncthreads();
    const unsigned above = aux[wid] + (inc - s);
#pragma unroll
    for (int i = 0; i < 16; ++i) hist[t * 16 + i] = loc[i] + above;   // suffix counts
    __syncthreads();
#pragma unroll
    for (int i = 0; i < 16; ++i) {
        const int B = t * 16 + i;
        if (hist[B] >= KEEP && hist[B + 1] < KEEP) {
            aux[16] = (unsigned)B;
            aux[17] = hist[B + 1];
        }
    }
    __syncthreads();
    const unsigned B1 = aux[16];
    const unsigned base1 = aux[17];
    __syncthreads();

    // ---- level 2: (bits >> 8) & 0xFF within bucket B1 ----
    if (t < 257) hist[t] = 0u;
    __syncthreads();
#pragma unroll
    for (int j = 0; j < 16; ++j)
        if ((bits[j] >> 16) == B1) atomicAdd(&hist[(bits[j] >> 8) & 0xFFu], 1u);
    __syncthreads();
    if (wid == 0) {
        unsigned l4[4];
        unsigned ss = 0;
#pragma unroll
        for (int i = 3; i >= 0; --i) { ss += hist[lane * 4 + i]; l4[i] = ss; }
        unsigned inc2 = ss;
#pragma unroll
        for (int off = 1; off < 64; off <<= 1) {
            const unsigned n = __shfl_down(inc2, off);
            if (lane + off < 64) inc2 += n;
        }
        const unsigned abv = inc2 - ss;
#pragma unroll
        for (int i = 0; i < 4; ++i) hist[lane * 4 + i] = l4[i] + abv;
        if (lane == 0) hist[256] = 0u;
    }
    __syncthreads();
    if (t < 256) {
        if (base1 + hist[t] >= KEEP && base1 + hist[t + 1] < KEEP) {
            aux[18] = (unsigned)t;
            aux[19] = base1 + hist[t + 1];
        }
    }
    __syncthreads();
    const unsigned b2 = aux[18];
    const unsigned base2 = aux[19];
    __syncthreads();

    // ---- level 3: bits & 0xFF within (B1, b2) ----
    const unsigned pfx = (B1 << 8) | b2;
    if (t < 257) hist[t] = 0u;
    __syncthreads();
#pragma unroll
    for (int j = 0; j < 16; ++j)
        if ((bits[j] >> 8) == pfx) atomicAdd(&hist[bits[j] & 0xFFu], 1u);
    __syncthreads();
    if (wid == 0) {
        unsigned l4[4];
        unsigned ss = 0;
#pragma unroll
        for (int i = 3; i >= 0; --i) { ss += hist[lane * 4 + i]; l4[i] = ss; }
        unsigned inc2 = ss;
#pragma unroll
        for (int off = 1; off < 64; off <<= 1) {
            const unsigned n = __shfl_down(inc2, off);
            if (lane + off < 64) inc2 += n;
        }
        const unsigned abv = inc2 - ss;
#pragma unroll
        for (int i = 0; i < 4; ++i) hist[lane * 4 + i] = l4[i] + abv;
        if (lane == 0) hist[256] = 0u;
    }
    __syncthreads();
    if (t < 256) {
        if (base2 + hist[t] >= KEEP && base2 + hist[t + 1] < KEEP) {
            aux[20] = (unsigned)t;
            aux[21] = base2 + hist[t + 1];
        }
    }
    __syncthreads();
    T   = (B1 << 16) | (b2 << 8) | aux[20];
    cGT = aux[21];
    __syncthreads();
}

// ---------------------------------------------------------------------------
// prep: pack W1 into MFMA-B-fragment lines, bf16. 128 blocks (kt x 8 segs).
// ---------------------------------------------------------------------------
__global__ __launch_bounds__(256) void prep_kernel(
    const float* __restrict__ W1, ushort* __restrict__ Wpk)
{
    const int kt  = blockIdx.x >> 3;          // 0..15
    const int idx = (blockIdx.x & 7) * 256 + threadIdx.x;   // 0..2047
    const int lane = idx & 63;
    const int g    = idx >> 6;                // 0..31
    const int h    = (g & 15) * 16 + (lane & 15);
    const int kb   = kt * 64 + (g >> 4) * 32 + (lane >> 4) * 8;
    ushort v[8];
#pragma unroll
    for (int j = 0; j < 8; ++j)
        v[j] = (ushort)bf16_rne(W1[(size_t)(kb + j) * HID + h]);
    *(uint4*)(Wpk + ((size_t)(kt * 32 + g) * 64 + lane) * 8) = *(uint4*)v;
}

// ---------------------------------------------------------------------------
// score: best-measured variant (r6): 3-slot circular LDS, counted vmcnt
// (never 0 in main loop), raw s_barrier. 512 thr = 8 waves, 128x256, BK=32.
// ---------------------------------------------------------------------------
__global__ __launch_bounds__(512, 4) void score_mfma(
    const float* __restrict__ x, const ushort* __restrict__ Wpk,
    const float* __restrict__ b1, const float* __restrict__ W2,
    const float* __restrict__ b2, float* __restrict__ scores,
    float* __restrict__ partials)
{
    __shared__ ushort AsAll[3 * ASLOT];
    __shared__ ushort BsAll[3 * BSLOT];

    const int t    = threadIdx.x;
    const int lane = t & 63;
    const int w    = t >> 6;         // 0..7
    const int wr   = w >> 2;         // 0..1  (64 rows each)
    const int wc   = w & 3;          // 0..3  (64 cols each)
    const int l15  = lane & 15;
    const int lk   = lane >> 4;
    const size_t row0 = (size_t)blockIdx.x * 128;

    const int arow = t >> 2;         // 0..127
    const int aq   = t & 3;          // 8-float chunk of 32-k slice
    const float* xbase = x + (row0 + arow) * DIM + aq * 8;

    f32x4 acc[4][4];
#pragma unroll
    for (int rf = 0; rf < 4; ++rf)
#pragma unroll
        for (int cf = 0; cf < 4; ++cf) acc[rf][cf] = (f32x4){0.f, 0.f, 0.f, 0.f};

    float4 p0a, p0b, p1a, p1b;       // two A prefetch register sets

#define ISSUEA(KT, PA, PB) { \
        const float4* xp = (const float4*)(xbase + (size_t)(KT) * BK); \
        PA = xp[0]; PB = xp[1]; }
#define CONVA(PA, PB, SLOT) { \
        ushort hb[8]; \
        hb[0] = (ushort)bf16_rne(PA.x); hb[1] = (ushort)bf16_rne(PA.y); \
        hb[2] = (ushort)bf16_rne(PA.z); hb[3] = (ushort)bf16_rne(PA.w); \
        hb[4] = (ushort)bf16_rne(PB.x); hb[5] = (ushort)bf16_rne(PB.y); \
        hb[6] = (ushort)bf16_rne(PB.z); hb[7] = (ushort)bf16_rne(PB.w); \
        *(uint4*)&AsAll[(SLOT) * ASLOT + arow * AP + aq * 8] = *(uint4*)&hb[0]; }
#define ISSUEB(KT, SLOT) { \
        _Pragma("unroll") \
        for (int i = 0; i < 2; ++i) { \
            const int g_ = w * 2 + i; \
            GLDS16(Wpk + (((size_t)(KT) * 16 + g_) * 64 + lane) * 8, \
                   &BsAll[(SLOT) * BSLOT + g_ * 512 + lane * 8]); \
        } }
#define COMPUTE(SLOT) { \
        bf16x8 Af[4]; \
        _Pragma("unroll") \
        for (int rf = 0; rf < 4; ++rf) { \
            const int row = wr * 64 + rf * 16 + l15; \
            Af[rf] = *(const bf16x8*)&AsAll[(SLOT) * ASLOT + row * AP + lk * 8]; \
        } \
        _Pragma("unroll") \
        for (int cf = 0; cf < 4; ++cf) { \
            const bf16x8 Bf = *(const bf16x8*)&BsAll[(SLOT) * BSLOT + (wc * 4 + cf) * 512 + lane * 8]; \
            acc[0][cf] = __builtin_amdgcn_mfma_f32_16x16x32_bf16(Af[0], Bf, acc[0][cf], 0, 0, 0); \
            acc[1][cf] = __builtin_amdgcn_mfma_f32_16x16x32_bf16(Af[1], Bf, acc[1][cf], 0, 0, 0); \
            acc[2][cf] = __builtin_amdgcn_mfma_f32_16x16x32_bf16(Af[2], Bf, acc[2][cf], 0, 0, 0); \
            acc[3][cf] = __builtin_amdgcn_mfma_f32_16x16x32_bf16(Af[3], Bf, acc[3][cf], 0, 0, 0); \
        } }

    // ---- prologue
    ISSUEB(0, 0);
    ISSUEA(0, p0a, p0b);
    ISSUEA(1, p1a, p1b);
    CONVA(p0a, p0b, 0);
    asm volatile("s_waitcnt lgkmcnt(0)" ::: "memory");
    __builtin_amdgcn_s_barrier();
    __builtin_amdgcn_sched_barrier(0);

    for (int kt = 0; kt < NKT; ++kt) {
        if (kt < NKT - 2) {
            if ((kt & 1) == 0) { ISSUEA(kt + 2, p0a, p0b); }
            else               { ISSUEA(kt + 2, p1a, p1b); }
        }
        if (kt < NKT - 1) {
            const int s1 = (kt + 1) % 3;
            ISSUEB(kt + 1, s1);
            if ((kt & 1) == 0) { CONVA(p1a, p1b, s1); }
            else               { CONVA(p0a, p0b, s1); }
        }
        if (kt < NKT - 2)       asm volatile("s_waitcnt vmcnt(4)" ::: "memory");
        else if (kt == NKT - 2) asm volatile("s_waitcnt vmcnt(2)" ::: "memory");
        else                    asm volatile("s_waitcnt vmcnt(0)" ::: "memory");
        asm volatile("s_waitcnt lgkmcnt(0)" ::: "memory");
        __builtin_amdgcn_s_barrier();
        __builtin_amdgcn_sched_barrier(0);
        COMPUTE(kt % 3);
    }

    // ---- epilogue (zb/rd aliased onto Bs slot 0)
    float* zb = (float*)&BsAll[0];        // [128][4]
    float* rd = (float*)&BsAll[1024];     // [128]
    float b1r[4], w2r[4];
#pragma unroll
    for (int cf = 0; cf < 4; ++cf) {
        const int col = wc * 64 + cf * 16 + l15;
        b1r[cf] = b1[col];
        w2r[cf] = W2[col];
    }
#pragma unroll
    for (int rf = 0; rf < 4; ++rf) {
#pragma unroll
        for (int j = 0; j < 4; ++j) {
            float z = 0.f;
#pragma unroll
            for (int cf = 0; cf < 4; ++cf)
                z = fmaf(fmaxf(acc[rf][cf][j] + b1r[cf], 0.f), w2r[cf], z);
            z += __shfl_xor(z, 1);
            z += __shfl_xor(z, 2);
            z += __shfl_xor(z, 4);
            z += __shfl_xor(z, 8);
            if (l15 == 0) zb[(wr * 64 + rf * 16 + lk * 4 + j) * 4 + wc] = z;
        }
    }
    __syncthreads();
    if (t < 128) {
        const float z = (zb[t * 4 + 0] + zb[t * 4 + 1]) + (zb[t * 4 + 2] + zb[t * 4 + 3]) + b2[0];
        const float s = 1.f / (1.f + expf(-z));
        scores[row0 + t] = s;
        rd[t] = fabsf(s - 0.5f);
    }
    __syncthreads();
    for (int off = 64; off > 0; off >>= 1) {
        if (t < off) rd[t] += rd[t + off];
        __syncthreads();
    }
    if (t == 0) partials[blockIdx.x] = rd[0];
}

// ---------------------------------------------------------------------------
// fixfind: blocks 0..3 = radix-select approx threshold + emit window rows.
// Block 4 = loss reduce over 512 partials (fused, saves a launch).
// ---------------------------------------------------------------------------
__global__ __launch_bounds__(1024) void fixfind_kernel(
    const float* __restrict__ scores, int* __restrict__ winList,
    int* __restrict__ winCnt, const float* __restrict__ partials,
    float* __restrict__ outLoss)
{
    const int b    = blockIdx.x;
    const int t    = threadIdx.x;
    const int lane = t & 63;
    const int wid  = t >> 6;
    __shared__ unsigned hist[16385];
    __shared__ unsigned aux[24];
    __shared__ unsigned wsum[16];

    if (b == BATCH) {
        // loss: -mean(|s-0.5|) from 512 score-block partials
        float* fr = (float*)hist;
        fr[t] = (t < 512) ? partials[t] : 0.f;
        __syncthreads();
        for (int off = 512; off > 0; off >>= 1) {
            if (t < off) fr[t] += fr[t + off];
            __syncthreads();
        }
        if (t == 0) outLoss[0] = -(fr[0] / (float)MROWS);
        return;
    }

    float sv[16];
    unsigned bits[16];
    const float4* sp = (const float4*)(scores + (size_t)b * N_TOK + t * 16);
#pragma unroll
    for (int j = 0; j < 4; ++j) {
        const float4 v = sp[j];
        sv[j * 4 + 0] = v.x; sv[j * 4 + 1] = v.y;
        sv[j * 4 + 2] = v.z; sv[j * 4 + 3] = v.w;
    }
#pragma unroll
    for (int j = 0; j < 16; ++j) bits[j] = __float_as_uint(sv[j]);

    unsigned T, cGT;
    radix_thresh(bits, t, lane, wid, hist, aux, T, cGT);
    const float sT = __uint_as_float(T);

    int cnt = 0;
    bool inw[16];
#pragma unroll
    for (int j = 0; j < 16; ++j) {
        inw[j] = fabsf(sv[j] - sT) <= DELTA;
        cnt += inw[j] ? 1 : 0;
    }
    unsigned inc = (unsigned)cnt;
#pragma unroll
    for (int off = 1; off < 64; off <<= 1) {
        const unsigned n = __shfl_up(inc, off);
        if (lane >= off) inc += n;
    }
    const unsigned excl = inc - (unsigned)cnt;
    if (lane == 63) wsum[wid] = inc;
    __syncthreads();
    if (t == 0) {
        unsigned s = 0;
        for (int w = 0; w < 16; ++w) { const unsigned tmp = wsum[w]; wsum[w] = s; s += tmp; }
        winCnt[b] = (int)(s > WCAP ? WCAP : s);
    }
    __syncthreads();
    unsigned pos = wsum[wid] + excl;
#pragma unroll
    for (int j = 0; j < 16; ++j) {
        if (inw[j]) {
            if (pos < WCAP) winList[b * WCAP + pos] = t * 16 + j;
            ++pos;
        }
    }
}

// ---------------------------------------------------------------------------
// fix2: exact f32 recompute of windowed rows, 8 rows/group, 1024 threads.
// ---------------------------------------------------------------------------
__global__ __launch_bounds__(1024) void fix2_kernel(
    const float* __restrict__ x, const float* __restrict__ W1,
    const float* __restrict__ b1, const float* __restrict__ W2,
    const float* __restrict__ b2, float* __restrict__ scores,
    const int* __restrict__ winList, const int* __restrict__ winCnt)
{
    __shared__ float xrT[1024][8];
    __shared__ float part[4][8][256];
    __shared__ int rows[8];

    const int t = threadIdx.x;
    int c[4], cum[5];
    cum[0] = 0;
    for (int b = 0; b < 4; ++b) {
        int cc = winCnt[b];
        if (cc > WCAP) cc = WCAP;
        if (cc < 0) cc = 0;
        c[b] = cc;
        cum[b + 1] = cum[b] + ((cc + 7) >> 3);
    }
    for (int g = blockIdx.x; g < cum[4]; g += gridDim.x) {
        int b = 0;
        while (g >= cum[b + 1]) ++b;
        const int gi   = g - cum[b];
        const int nval = min(8, c[b] - gi * 8);
        if (t < 8)
            rows[t] = winList[b * WCAP + gi * 8 + (t < nval ? t : 0)];
        __syncthreads();
        {
            const int r = t >> 7, c0 = (t & 127) * 8;
            const float* xp = x + ((size_t)b * N_TOK + rows[r]) * DIM + c0;
            const float4 a = ((const float4*)xp)[0], bq = ((const float4*)xp)[1];
            xrT[c0 + 0][r] = a.x;  xrT[c0 + 1][r] = a.y;
            xrT[c0 + 2][r] = a.z;  xrT[c0 + 3][r] = a.w;
            xrT[c0 + 4][r] = bq.x; xrT[c0 + 5][r] = bq.y;
            xrT[c0 + 6][r] = bq.z; xrT[c0 + 7][r] = bq.w;
        }
        __syncthreads();
        const int h = t & 255, q = t >> 8;
        float a8[8];
#pragma unroll
        for (int r = 0; r < 8; ++r) a8[r] = 0.f;
        const int k0 = q * 256;
        for (int k = 0; k < 256; ++k) {
            const float wv = W1[(size_t)(k0 + k) * HID + h];
            const float4 xa = *(const float4*)&xrT[k0 + k][0];
            const float4 xb = *(const float4*)&xrT[k0 + k][4];
            a8[0] = fmaf(xa.x, wv, a8[0]); a8[1] = fmaf(xa.y, wv, a8[1]);
            a8[2] = fmaf(xa.z, wv, a8[2]); a8[3] = fmaf(xa.w, wv, a8[3]);
            a8[4] = fmaf(xb.x, wv, a8[4]); a8[5] = fmaf(xb.y, wv, a8[5]);
            a8[6] = fmaf(xb.z, wv, a8[6]); a8[7] = fmaf(xb.w, wv, a8[7]);
        }
#pragma unroll
        for (int r = 0; r < 8; ++r) part[q][r][h] = a8[r];
        __syncthreads();
        const int wid = t >> 6, lane = t & 63;
        if (wid < 8) {
            const int r = wid;
            float v = 0.f;
#pragma unroll
            for (int i = 0; i < 4; ++i) {
                const int hc = i * 64 + lane;
                float hv = (part[0][r][hc] + part[1][r][hc]) + (part[2][r][hc] + part[3][r][hc]);
                hv = fmaxf(hv + b1[hc], 0.f);
                v = fmaf(hv, W2[hc], v);
            }
            v += __shfl_xor(v, 32); v += __shfl_xor(v, 16); v += __shfl_xor(v, 8);
            v += __shfl_xor(v, 4);  v += __shfl_xor(v, 2);  v += __shfl_xor(v, 1);
            if (lane == 0 && r < nval)
                scores[(size_t)b * N_TOK + rows[r]] = 1.f / (1.f + expf(-(v + b2[0])));
        }
        __syncthreads();
    }
}

// ---------------------------------------------------------------------------
// select: radix-select exact top-k per batch on corrected scores.
// ---------------------------------------------------------------------------
__global__ __launch_bounds__(1024) void select_kernel(
    const float* __restrict__ scores, int* __restrict__ idxList)
{
    const int b    = blockIdx.x;
    const int t    = threadIdx.x;
    const int lane = t & 63;
    const int wid  = t >> 6;
    __shared__ unsigned hist[16385];
    __shared__ unsigned aux[24];
    __shared__ unsigned wsum[16];

    unsigned bits[16];
    const float4* sp = (const float4*)(scores + (size_t)b * N_TOK + t * 16);
#pragma unroll
    for (int j = 0; j < 4; ++j) {
        const float4 v = sp[j];
        bits[j * 4 + 0] = __float_as_uint(v.x);
        bits[j * 4 + 1] = __float_as_uint(v.y);
        bits[j * 4 + 2] = __float_as_uint(v.z);
        bits[j * 4 + 3] = __float_as_uint(v.w);
    }

    unsigned T, cGT;
    radix_thresh(bits, t, lane, wid, hist, aux, T, cGT);
    const unsigned need = KEEP - cGT;

    unsigned pre[16];
    unsigned run = 0;
#pragma unroll
    for (int j = 0; j < 16; ++j) {
        pre[j] = run;
        const unsigned gt = (bits[j] > T) ? 1u : 0u;
        const unsigned eq = (bits[j] == T) ? 1u : 0u;
        run += gt | (eq << 16);
    }
    unsigned inc = run;
#pragma unroll
    for (int off = 1; off < 64; off <<= 1) {
        const unsigned n = __shfl_up(inc, off);
        if (lane >= off) inc += n;
    }
    const unsigned waveExcl = inc - run;
    if (lane == 63) wsum[wid] = inc;
    __syncthreads();
    if (t == 0) {
        unsigned s = 0;
        for (int w = 0; w < 16; ++w) { const unsigned tmp = wsum[w]; wsum[w] = s; s += tmp; }
    }
    __syncthreads();
    const unsigned base = wsum[wid] + waveExcl;

#pragma unroll
    for (int j = 0; j < 16; ++j) {
        const unsigned pe    = base + pre[j];
        const unsigned tieR  = pe >> 16;
        const unsigned posGT = pe & 0xFFFFu;
        const bool gt = bits[j] > T;
        const bool eq = bits[j] == T;
        if (gt || (eq && tieR < need)) {
            const unsigned pos = posGT + (tieR < need ? tieR : need);
            idxList[(size_t)b * KEEP + pos] = t * 16 + j;
        }
    }
}

// ---------------------------------------------------------------------------
// gather: weighted gather, float4 (HBM-bound, near roofline).
// ---------------------------------------------------------------------------
__global__ __launch_bounds__(256) void gather_kernel(
    const float* __restrict__ x, const float* __restrict__ scores,
    const int* __restrict__ idxList, float* __restrict__ out)
{
    const int t = threadIdx.x;
#pragma unroll
    for (int q = 0; q < 4; ++q) {
        const int orow = blockIdx.x * 4 + q;
        const int b    = orow / KEEP;
        const int idx  = idxList[orow];
        const float s  = scores[(size_t)b * N_TOK + idx];
        const float4 v = *(const float4*)(x + (((size_t)b * N_TOK + idx) << 10) + t * 4);
        float4 o;
        o.x = v.x * s; o.y = v.y * s; o.z = v.z * s; o.w = v.w * s;
        *(float4*)(out + ((size_t)orow << 10) + t * 4) = o;
    }
}

extern "C" void kernel_launch(void* const* d_in, const int* in_sizes, int n_in,
                              void* d_out, int out_size, void* d_ws, size_t ws_size,
                              hipStream_t stream)
{
    const float* x  = (const float*)d_in[0];
    const float* W1 = (const float*)d_in[1];
    const float* b1 = (const float*)d_in[2];
    const float* W2 = (const float*)d_in[3];
    const float* b2 = (const float*)d_in[4];
    float* out = (float*)d_out;

    char* ws = (char*)d_ws;
    float* scores   = (float*)ws;                 // 262144 B
    float* partials = (float*)(ws + 262144);      // 4096 B (512 used)
    int*   idxList  = (int*)(ws + 266240);        // 183488 B
    ushort* Wpk     = (ushort*)(ws + 458752);     // 524288 B
    int*   winList  = (int*)(ws + 983040);        // 65536 B
    int*   winCnt   = (int*)(ws + 1048576);       // 16 B

    prep_kernel<<<128, 256, 0, stream>>>(W1, Wpk);
    score_mfma<<<MROWS / 128, 512, 0, stream>>>(x, Wpk, b1, W2, b2, scores, partials);
    fixfind_kernel<<<BATCH + 1, 1024, 0, stream>>>(scores, winList, winCnt,
                                                   partials, out + (size_t)BATCH * KEEP * DIM);
    fix2_kernel<<<256, 1024, 0, stream>>>(x, W1, b1, W2, b2, scores, winList, winCnt);
    select_kernel<<<BATCH, 1024, 0, stream>>>(scores, idxList);
    gather_kernel<<<KEEP, 256, 0, stream>>>(x, scores, idxList, out);
}

// Round 14
// 197.962 us; speedup vs baseline: 1.6090x; 1.0053x over previous
//
#include <hip/hip_runtime.h>
#include <hip/hip_bf16.h>
#include <math.h>

#define N_TOK 16384
#define BATCH 4
#define DIM   1024
#define HID   256
#define KEEP  11468            // int(16384 * 0.7)
#define MROWS 65536
#define BM    256              // rows per score block
#define BK    32
#define NKT   (DIM / BK)       // 32 K-iters
#define DELTA 2.5e-3f          // exact-recompute window (10 sigma of bf16 score err)
#define WCAP  4096             // max window rows per batch
#define AP    40               // A row pitch in ushorts (80B: 2-way bank alias = free)
#define ASLOT (BM * AP)        // 10240 ushorts per A slot (20KB)
#define BSLOT (16 * 512)       // 8192 ushorts per B slot (16KB)

typedef __attribute__((ext_vector_type(8))) short bf16x8;
typedef __attribute__((ext_vector_type(4))) float f32x4;

__device__ inline unsigned bf16_rne(float f) {
    unsigned u = __float_as_uint(f);
    return (u + 0x7FFFu + ((u >> 16) & 1u)) >> 16;
}

#define GLDS16(gp, lp) __builtin_amdgcn_global_load_lds( \
    (const __attribute__((address_space(1))) void*)(gp), \
    (__attribute__((address_space(3))) void*)(lp), 16, 0, 0)

// ---------------------------------------------------------------------------
// radix_thresh: exact top-k threshold over 16384 positive-float bit patterns
// (16/thread, 1024-thread block). 3-level radix, suffix-scanned histograms.
// ---------------------------------------------------------------------------
__device__ __forceinline__ void radix_thresh(
    const unsigned bits[16], const int t, const int lane, const int wid,
    unsigned* hist, unsigned* aux, unsigned& T, unsigned& cGT)
{
    // ---- level 1: buckets = bits >> 16 ----
#pragma unroll
    for (int i = 0; i < 16; ++i) hist[t * 16 + i] = 0u;
    if (t == 0) hist[16384] = 0u;
    __syncthreads();
#pragma unroll
    for (int j = 0; j < 16; ++j) atomicAdd(&hist[bits[j] >> 16], 1u);
    __syncthreads();
    unsigned loc[16];
    unsigned s = 0;
#pragma unroll
    for (int i = 15; i >= 0; --i) { s += hist[t * 16 + i]; loc[i] = s; }
    unsigned inc = s;
#pragma unroll
    for (int off = 1; off < 64; off <<= 1) {
        const unsigned n = __shfl_down(inc, off);
        if (lane + off < 64) inc += n;
    }
    if (lane == 0) aux[wid] = inc;
    __syncthreads();
    if (t == 0) {
        unsigned run = 0;
        for (int w = 15; w >= 0; --w) { const unsigned tmp = aux[w]; aux[w] = run; run += tmp; }
    }
    __syncthreads();
    const unsigned above = aux[wid] + (inc - s);
#pragma unroll
    for (int i = 0; i < 16; ++i) hist[t * 16 + i] = loc[i] + above;
    __syncthreads();
#pragma unroll
    for (int i = 0; i < 16; ++i) {
        const int B = t * 16 + i;
        if (hist[B] >= KEEP && hist[B + 1] < KEEP) {
            aux[16] = (unsigned)B;
            aux[17] = hist[B + 1];
        }
    }
    __syncthreads();
    const unsigned B1 = aux[16];
    const unsigned base1 = aux[17];
    __syncthreads();

    // ---- level 2 ----
    if (t < 257) hist[t] = 0u;
    __syncthreads();
#pragma unroll
    for (int j = 0; j < 16; ++j)
        if ((bits[j] >> 16) == B1) atomicAdd(&hist[(bits[j] >> 8) & 0xFFu], 1u);
    __syncthreads();
    if (wid == 0) {
        unsigned l4[4];
        unsigned ss = 0;
#pragma unroll
        for (int i = 3; i >= 0; --i) { ss += hist[lane * 4 + i]; l4[i] = ss; }
        unsigned inc2 = ss;
#pragma unroll
        for (int off = 1; off < 64; off <<= 1) {
            const unsigned n = __shfl_down(inc2, off);
            if (lane + off < 64) inc2 += n;
        }
        const unsigned abv = inc2 - ss;
#pragma unroll
        for (int i = 0; i < 4; ++i) hist[lane * 4 + i] = l4[i] + abv;
        if (lane == 0) hist[256] = 0u;
    }
    __syncthreads();
    if (t < 256) {
        if (base1 + hist[t] >= KEEP && base1 + hist[t + 1] < KEEP) {
            aux[18] = (unsigned)t;
            aux[19] = base1 + hist[t + 1];
        }
    }
    __syncthreads();
    const unsigned b2 = aux[18];
    const unsigned base2 = aux[19];
    __syncthreads();

    // ---- level 3 ----
    const unsigned pfx = (B1 << 8) | b2;
    if (t < 257) hist[t] = 0u;
    __syncthreads();
#pragma unroll
    for (int j = 0; j < 16; ++j)
        if ((bits[j] >> 8) == pfx) atomicAdd(&hist[bits[j] & 0xFFu], 1u);
    __syncthreads();
    if (wid == 0) {
        unsigned l4[4];
        unsigned ss = 0;
#pragma unroll
        for (int i = 3; i >= 0; --i) { ss += hist[lane * 4 + i]; l4[i] = ss; }
        unsigned inc2 = ss;
#pragma unroll
        for (int off = 1; off < 64; off <<= 1) {
            const unsigned n = __shfl_down(inc2, off);
            if (lane + off < 64) inc2 += n;
        }
        const unsigned abv = inc2 - ss;
#pragma unroll
        for (int i = 0; i < 4; ++i) hist[lane * 4 + i] = l4[i] + abv;
        if (lane == 0) hist[256] = 0u;
    }
    __syncthreads();
    if (t < 256) {
        if (base2 + hist[t] >= KEEP && base2 + hist[t + 1] < KEEP) {
            aux[20] = (unsigned)t;
            aux[21] = base2 + hist[t + 1];
        }
    }
    __syncthreads();
    T   = (B1 << 16) | (b2 << 8) | aux[20];
    cGT = aux[21];
    __syncthreads();
}

// ---------------------------------------------------------------------------
// prep: pack W1 into MFMA-B-fragment lines, bf16. 128 blocks.
// ---------------------------------------------------------------------------
__global__ __launch_bounds__(256) void prep_kernel(
    const float* __restrict__ W1, ushort* __restrict__ Wpk)
{
    const int kt  = blockIdx.x >> 3;
    const int idx = (blockIdx.x & 7) * 256 + threadIdx.x;
    const int lane = idx & 63;
    const int g    = idx >> 6;
    const int h    = (g & 15) * 16 + (lane & 15);
    const int kb   = kt * 64 + (g >> 4) * 32 + (lane >> 4) * 8;
    ushort v[8];
#pragma unroll
    for (int j = 0; j < 8; ++j)
        v[j] = (ushort)bf16_rne(W1[(size_t)(kb + j) * HID + h]);
    *(uint4*)(Wpk + ((size_t)(kt * 32 + g) * 64 + lane) * 8) = *(uint4*)v;
}

// ---------------------------------------------------------------------------
// score: r6's 3-slot counted-vmcnt structure x r11's BM=256 tile.
// 1024 thr = 16 waves (4 wr x 4 wc), wave tile 64x64 (acc[4][4]=64 VGPR).
// grid = 256 = 1 block/CU. LDS 108KB (3x20KB A + 3x16KB B).
// B traffic per block amortized over 256 rows (half of r6's per-row cost).
// Counted vmcnt (3/1/0), never 0 in main loop; loads span barriers.
// ---------------------------------------------------------------------------
__global__ __launch_bounds__(1024, 4) void score_mfma(
    const float* __restrict__ x, const ushort* __restrict__ Wpk,
    const float* __restrict__ b1, const float* __restrict__ W2,
    const float* __restrict__ b2, float* __restrict__ scores,
    float* __restrict__ partials)
{
    __shared__ ushort AsAll[3 * ASLOT];
    __shared__ ushort BsAll[3 * BSLOT];

    const int t    = threadIdx.x;
    const int lane = t & 63;
    const int w    = t >> 6;         // 0..15
    const int wr   = w >> 2;         // 0..3  (64 rows each)
    const int wc   = w & 3;          // 0..3  (64 cols each)
    const int l15  = lane & 15;
    const int lk   = lane >> 4;
    const size_t row0 = (size_t)blockIdx.x * BM;

    const int arow = t >> 2;         // 0..255
    const int aq   = t & 3;          // 8-float chunk of 32-k slice
    const float* xbase = x + (row0 + arow) * DIM + aq * 8;

    f32x4 acc[4][4];
#pragma unroll
    for (int rf = 0; rf < 4; ++rf)
#pragma unroll
        for (int cf = 0; cf < 4; ++cf) acc[rf][cf] = (f32x4){0.f, 0.f, 0.f, 0.f};

    float4 p0a, p0b, p1a, p1b;       // two A prefetch register sets

#define ISSUEA(KT, PA, PB) { \
        const float4* xp = (const float4*)(xbase + (size_t)(KT) * BK); \
        PA = xp[0]; PB = xp[1]; }
#define CONVA(PA, PB, SLOT) { \
        ushort hb[8]; \
        hb[0] = (ushort)bf16_rne(PA.x); hb[1] = (ushort)bf16_rne(PA.y); \
        hb[2] = (ushort)bf16_rne(PA.z); hb[3] = (ushort)bf16_rne(PA.w); \
        hb[4] = (ushort)bf16_rne(PB.x); hb[5] = (ushort)bf16_rne(PB.y); \
        hb[6] = (ushort)bf16_rne(PB.z); hb[7] = (ushort)bf16_rne(PB.w); \
        *(uint4*)&AsAll[(SLOT) * ASLOT + arow * AP + aq * 8] = *(uint4*)&hb[0]; }
#define ISSUEB(KT, SLOT) { \
        GLDS16(Wpk + (((size_t)(KT) * 16 + w) * 64 + lane) * 8, \
               &BsAll[(SLOT) * BSLOT + w * 512 + lane * 8]); }
#define COMPUTE(SLOT) { \
        bf16x8 Af[4]; \
        _Pragma("unroll") \
        for (int rf = 0; rf < 4; ++rf) { \
            const int row = wr * 64 + rf * 16 + l15; \
            Af[rf] = *(const bf16x8*)&AsAll[(SLOT) * ASLOT + row * AP + lk * 8]; \
        } \
        _Pragma("unroll") \
        for (int cf = 0; cf < 4; ++cf) { \
            const bf16x8 Bf = *(const bf16x8*)&BsAll[(SLOT) * BSLOT + (wc * 4 + cf) * 512 + lane * 8]; \
            acc[0][cf] = __builtin_amdgcn_mfma_f32_16x16x32_bf16(Af[0], Bf, acc[0][cf], 0, 0, 0); \
            acc[1][cf] = __builtin_amdgcn_mfma_f32_16x16x32_bf16(Af[1], Bf, acc[1][cf], 0, 0, 0); \
            acc[2][cf] = __builtin_amdgcn_mfma_f32_16x16x32_bf16(Af[2], Bf, acc[2][cf], 0, 0, 0); \
            acc[3][cf] = __builtin_amdgcn_mfma_f32_16x16x32_bf16(Af[3], Bf, acc[3][cf], 0, 0, 0); \
        } }

    // ---- prologue
    ISSUEB(0, 0);
    ISSUEA(0, p0a, p0b);
    ISSUEA(1, p1a, p1b);
    CONVA(p0a, p0b, 0);
    asm volatile("s_waitcnt lgkmcnt(0)" ::: "memory");
    __builtin_amdgcn_s_barrier();
    __builtin_amdgcn_sched_barrier(0);

    for (int kt = 0; kt < NKT; ++kt) {
        if (kt < NKT - 2) {
            if ((kt & 1) == 0) { ISSUEA(kt + 2, p0a, p0b); }
            else               { ISSUEA(kt + 2, p1a, p1b); }
        }
        if (kt < NKT - 1) {
            const int s1 = (kt + 1) % 3;
            ISSUEB(kt + 1, s1);
            if ((kt & 1) == 0) { CONVA(p1a, p1b, s1); }
            else               { CONVA(p0a, p0b, s1); }
        }
        // in-flight after issue: A(kt+2) x2 + B(kt+1) x1 = 3 newest
        if (kt < NKT - 2)       asm volatile("s_waitcnt vmcnt(3)" ::: "memory");
        else if (kt == NKT - 2) asm volatile("s_waitcnt vmcnt(1)" ::: "memory");
        else                    asm volatile("s_waitcnt vmcnt(0)" ::: "memory");
        asm volatile("s_waitcnt lgkmcnt(0)" ::: "memory");
        __builtin_amdgcn_s_barrier();
        __builtin_amdgcn_sched_barrier(0);
        COMPUTE(kt % 3);
    }

    // ---- epilogue: z = sum_h relu(C + b1) * W2 (zb/rd aliased onto Bs)
    float* zb = (float*)&BsAll[0];        // [256][4] = 4KB
    float* rd = (float*)&BsAll[2048];     // [256] floats
    float b1r[4], w2r[4];
#pragma unroll
    for (int cf = 0; cf < 4; ++cf) {
        const int col = wc * 64 + cf * 16 + l15;
        b1r[cf] = b1[col];
        w2r[cf] = W2[col];
    }
#pragma unroll
    for (int rf = 0; rf < 4; ++rf) {
#pragma unroll
        for (int j = 0; j < 4; ++j) {
            float z = 0.f;
#pragma unroll
            for (int cf = 0; cf < 4; ++cf)
                z = fmaf(fmaxf(acc[rf][cf][j] + b1r[cf], 0.f), w2r[cf], z);
            z += __shfl_xor(z, 1);
            z += __shfl_xor(z, 2);
            z += __shfl_xor(z, 4);
            z += __shfl_xor(z, 8);
            if (l15 == 0) zb[(wr * 64 + rf * 16 + lk * 4 + j) * 4 + wc] = z;
        }
    }
    __syncthreads();
    if (t < BM) {
        const float z = (zb[t * 4 + 0] + zb[t * 4 + 1]) + (zb[t * 4 + 2] + zb[t * 4 + 3]) + b2[0];
        const float s = 1.f / (1.f + expf(-z));
        scores[row0 + t] = s;
        rd[t] = fabsf(s - 0.5f);
    }
    __syncthreads();
    for (int off = 128; off > 0; off >>= 1) {
        if (t < off && t + off < BM) rd[t] += rd[t + off];
        __syncthreads();
    }
    if (t == 0) partials[blockIdx.x] = rd[0];
}

// ---------------------------------------------------------------------------
// fixfind: blocks 0..3 = radix threshold + window emit; block 4 = loss.
// ---------------------------------------------------------------------------
__global__ __launch_bounds__(1024) void fixfind_kernel(
    const float* __restrict__ scores, int* __restrict__ winList,
    int* __restrict__ winCnt, const float* __restrict__ partials,
    float* __restrict__ outLoss)
{
    const int b    = blockIdx.x;
    const int t    = threadIdx.x;
    const int lane = t & 63;
    const int wid  = t >> 6;
    __shared__ unsigned hist[16385];
    __shared__ unsigned aux[24];
    __shared__ unsigned wsum[16];

    if (b == BATCH) {
        float* fr = (float*)hist;
        fr[t] = (t < 256) ? partials[t] : 0.f;
        __syncthreads();
        for (int off = 512; off > 0; off >>= 1) {
            if (t < off) fr[t] += fr[t + off];
            __syncthreads();
        }
        if (t == 0) outLoss[0] = -(fr[0] / (float)MROWS);
        return;
    }

    float sv[16];
    unsigned bits[16];
    const float4* sp = (const float4*)(scores + (size_t)b * N_TOK + t * 16);
#pragma unroll
    for (int j = 0; j < 4; ++j) {
        const float4 v = sp[j];
        sv[j * 4 + 0] = v.x; sv[j * 4 + 1] = v.y;
        sv[j * 4 + 2] = v.z; sv[j * 4 + 3] = v.w;
    }
#pragma unroll
    for (int j = 0; j < 16; ++j) bits[j] = __float_as_uint(sv[j]);

    unsigned T, cGT;
    radix_thresh(bits, t, lane, wid, hist, aux, T, cGT);
    const float sT = __uint_as_float(T);

    int cnt = 0;
    bool inw[16];
#pragma unroll
    for (int j = 0; j < 16; ++j) {
        inw[j] = fabsf(sv[j] - sT) <= DELTA;
        cnt += inw[j] ? 1 : 0;
    }
    unsigned inc = (unsigned)cnt;
#pragma unroll
    for (int off = 1; off < 64; off <<= 1) {
        const unsigned n = __shfl_up(inc, off);
        if (lane >= off) inc += n;
    }
    const unsigned excl = inc - (unsigned)cnt;
    if (lane == 63) wsum[wid] = inc;
    __syncthreads();
    if (t == 0) {
        unsigned s = 0;
        for (int w = 0; w < 16; ++w) { const unsigned tmp = wsum[w]; wsum[w] = s; s += tmp; }
        winCnt[b] = (int)(s > WCAP ? WCAP : s);
    }
    __syncthreads();
    unsigned pos = wsum[wid] + excl;
#pragma unroll
    for (int j = 0; j < 16; ++j) {
        if (inw[j]) {
            if (pos < WCAP) winList[b * WCAP + pos] = t * 16 + j;
            ++pos;
        }
    }
}

// ---------------------------------------------------------------------------
// fix2: exact f32 recompute of windowed rows, 8 rows/group, 1024 threads.
// ---------------------------------------------------------------------------
__global__ __launch_bounds__(1024) void fix2_kernel(
    const float* __restrict__ x, const float* __restrict__ W1,
    const float* __restrict__ b1, const float* __restrict__ W2,
    const float* __restrict__ b2, float* __restrict__ scores,
    const int* __restrict__ winList, const int* __restrict__ winCnt)
{
    __shared__ float xrT[1024][8];
    __shared__ float part[4][8][256];
    __shared__ int rows[8];

    const int t = threadIdx.x;
    int c[4], cum[5];
    cum[0] = 0;
    for (int b = 0; b < 4; ++b) {
        int cc = winCnt[b];
        if (cc > WCAP) cc = WCAP;
        if (cc < 0) cc = 0;
        c[b] = cc;
        cum[b + 1] = cum[b] + ((cc + 7) >> 3);
    }
    for (int g = blockIdx.x; g < cum[4]; g += gridDim.x) {
        int b = 0;
        while (g >= cum[b + 1]) ++b;
        const int gi   = g - cum[b];
        const int nval = min(8, c[b] - gi * 8);
        if (t < 8)
            rows[t] = winList[b * WCAP + gi * 8 + (t < nval ? t : 0)];
        __syncthreads();
        {
            const int r = t >> 7, c0 = (t & 127) * 8;
            const float* xp = x + ((size_t)b * N_TOK + rows[r]) * DIM + c0;
            const float4 a = ((const float4*)xp)[0], bq = ((const float4*)xp)[1];
            xrT[c0 + 0][r] = a.x;  xrT[c0 + 1][r] = a.y;
            xrT[c0 + 2][r] = a.z;  xrT[c0 + 3][r] = a.w;
            xrT[c0 + 4][r] = bq.x; xrT[c0 + 5][r] = bq.y;
            xrT[c0 + 6][r] = bq.z; xrT[c0 + 7][r] = bq.w;
        }
        __syncthreads();
        const int h = t & 255, q = t >> 8;
        float a8[8];
#pragma unroll
        for (int r = 0; r < 8; ++r) a8[r] = 0.f;
        const int k0 = q * 256;
        for (int k = 0; k < 256; ++k) {
            const float wv = W1[(size_t)(k0 + k) * HID + h];
            const float4 xa = *(const float4*)&xrT[k0 + k][0];
            const float4 xb = *(const float4*)&xrT[k0 + k][4];
            a8[0] = fmaf(xa.x, wv, a8[0]); a8[1] = fmaf(xa.y, wv, a8[1]);
            a8[2] = fmaf(xa.z, wv, a8[2]); a8[3] = fmaf(xa.w, wv, a8[3]);
            a8[4] = fmaf(xb.x, wv, a8[4]); a8[5] = fmaf(xb.y, wv, a8[5]);
            a8[6] = fmaf(xb.z, wv, a8[6]); a8[7] = fmaf(xb.w, wv, a8[7]);
        }
#pragma unroll
        for (int r = 0; r < 8; ++r) part[q][r][h] = a8[r];
        __syncthreads();
        const int wid = t >> 6, lane = t & 63;
        if (wid < 8) {
            const int r = wid;
            float v = 0.f;
#pragma unroll
            for (int i = 0; i < 4; ++i) {
                const int hc = i * 64 + lane;
                float hv = (part[0][r][hc] + part[1][r][hc]) + (part[2][r][hc] + part[3][r][hc]);
                hv = fmaxf(hv + b1[hc], 0.f);
                v = fmaf(hv, W2[hc], v);
            }
            v += __shfl_xor(v, 32); v += __shfl_xor(v, 16); v += __shfl_xor(v, 8);
            v += __shfl_xor(v, 4);  v += __shfl_xor(v, 2);  v += __shfl_xor(v, 1);
            if (lane == 0 && r < nval)
                scores[(size_t)b * N_TOK + rows[r]] = 1.f / (1.f + expf(-(v + b2[0])));
        }
        __syncthreads();
    }
}

// ---------------------------------------------------------------------------
// select: radix-select exact top-k per batch on corrected scores.
// ---------------------------------------------------------------------------
__global__ __launch_bounds__(1024) void select_kernel(
    const float* __restrict__ scores, int* __restrict__ idxList)
{
    const int b    = blockIdx.x;
    const int t    = threadIdx.x;
    const int lane = t & 63;
    const int wid  = t >> 6;
    __shared__ unsigned hist[16385];
    __shared__ unsigned aux[24];
    __shared__ unsigned wsum[16];

    unsigned bits[16];
    const float4* sp = (const float4*)(scores + (size_t)b * N_TOK + t * 16);
#pragma unroll
    for (int j = 0; j < 4; ++j) {
        const float4 v = sp[j];
        bits[j * 4 + 0] = __float_as_uint(v.x);
        bits[j * 4 + 1] = __float_as_uint(v.y);
        bits[j * 4 + 2] = __float_as_uint(v.z);
        bits[j * 4 + 3] = __float_as_uint(v.w);
    }

    unsigned T, cGT;
    radix_thresh(bits, t, lane, wid, hist, aux, T, cGT);
    const unsigned need = KEEP - cGT;

    unsigned pre[16];
    unsigned run = 0;
#pragma unroll
    for (int j = 0; j < 16; ++j) {
        pre[j] = run;
        const unsigned gt = (bits[j] > T) ? 1u : 0u;
        const unsigned eq = (bits[j] == T) ? 1u : 0u;
        run += gt | (eq << 16);
    }
    unsigned inc = run;
#pragma unroll
    for (int off = 1; off < 64; off <<= 1) {
        const unsigned n = __shfl_up(inc, off);
        if (lane >= off) inc += n;
    }
    const unsigned waveExcl = inc - run;
    if (lane == 63) wsum[wid] = inc;
    __syncthreads();
    if (t == 0) {
        unsigned s = 0;
        for (int w = 0; w < 16; ++w) { const unsigned tmp = wsum[w]; wsum[w] = s; s += tmp; }
    }
    __syncthreads();
    const unsigned base = wsum[wid] + waveExcl;

#pragma unroll
    for (int j = 0; j < 16; ++j) {
        const unsigned pe    = base + pre[j];
        const unsigned tieR  = pe >> 16;
        const unsigned posGT = pe & 0xFFFFu;
        const bool gt = bits[j] > T;
        const bool eq = bits[j] == T;
        if (gt || (eq && tieR < need)) {
            const unsigned pos = posGT + (tieR < need ? tieR : need);
            idxList[(size_t)b * KEEP + pos] = t * 16 + j;
        }
    }
}

// ---------------------------------------------------------------------------
// gather: weighted gather, float4 (HBM-bound, near roofline).
// ---------------------------------------------------------------------------
__global__ __launch_bounds__(256) void gather_kernel(
    const float* __restrict__ x, const float* __restrict__ scores,
    const int* __restrict__ idxList, float* __restrict__ out)
{
    const int t = threadIdx.x;
#pragma unroll
    for (int q = 0; q < 4; ++q) {
        const int orow = blockIdx.x * 4 + q;
        const int b    = orow / KEEP;
        const int idx  = idxList[orow];
        const float s  = scores[(size_t)b * N_TOK + idx];
        const float4 v = *(const float4*)(x + (((size_t)b * N_TOK + idx) << 10) + t * 4);
        float4 o;
        o.x = v.x * s; o.y = v.y * s; o.z = v.z * s; o.w = v.w * s;
        *(float4*)(out + ((size_t)orow << 10) + t * 4) = o;
    }
}

extern "C" void kernel_launch(void* const* d_in, const int* in_sizes, int n_in,
                              void* d_out, int out_size, void* d_ws, size_t ws_size,
                              hipStream_t stream)
{
    const float* x  = (const float*)d_in[0];
    const float* W1 = (const float*)d_in[1];
    const float* b1 = (const float*)d_in[2];
    const float* W2 = (const float*)d_in[3];
    const float* b2 = (const float*)d_in[4];
    float* out = (float*)d_out;

    char* ws = (char*)d_ws;
    float* scores   = (float*)ws;                 // 262144 B
    float* partials = (float*)(ws + 262144);      // 4096 B (256 used)
    int*   idxList  = (int*)(ws + 266240);        // 183488 B
    ushort* Wpk     = (ushort*)(ws + 458752);     // 524288 B
    int*   winList  = (int*)(ws + 983040);        // 65536 B
    int*   winCnt   = (int*)(ws + 1048576);       // 16 B

    prep_kernel<<<128, 256, 0, stream>>>(W1, Wpk);
    score_mfma<<<MROWS / BM, 1024, 0, stream>>>(x, Wpk, b1, W2, b2, scores, partials);
    fixfind_kernel<<<BATCH + 1, 1024, 0, stream>>>(scores, winList, winCnt,
                                                   partials, out + (size_t)BATCH * KEEP * DIM);
    fix2_kernel<<<256, 1024, 0, stream>>>(x, W1, b1, W2, b2, scores, winList, winCnt);
    select_kernel<<<BATCH, 1024, 0, stream>>>(scores, idxList);
    gather_kernel<<<KEEP, 256, 0, stream>>>(x, scores, idxList, out);
}